// Round 7
// baseline (102.479 us; speedup 1.0000x reference)
//
#include <hip/hip_runtime.h>
#include <math.h>
#include <stdint.h>

#define NS    16
#define HWSZ  409600
#define NF4   102400      // float4s per sample
#define NBIN  128
#define SLW   (3*NBIN + 8) // words per block slice: hist cnt/s1/s2 + 8 scalar slots
#define CAP   4096
#define BCAP  512         // per-block LDS candidate staging
#define SBPS  200         // blocks per sample (contiguous 512-float4 chunks)
#define PADI  32          // ints per sample for padded atomic counter (128 B)

typedef unsigned long long u64;

__device__ __forceinline__ unsigned fkey(float f) {
    unsigned u = __float_as_uint(f);
    if (u == 0x80000000u) u = 0u;                 // canonicalize -0
    return (u & 0x80000000u) ? ~u : (u | 0x80000000u);
}

// bce1: BCE on p; bce2: BCE on sigmoid(50(p-t)); both with 1e-7 clipping
__device__ __forceinline__ void bce_pair(float pv, float tv, bool tc, float& o1, float& o2) {
    float pc = fminf(fmaxf(pv, 1e-7f), 1.0f - 1e-7f);
    float a = tc ? pc : 1.0f - pc;
    o1 = -__logf(a);
    float x = 50.0f * (pv - tv);
    float y = tc ? -x : x;
    float t2 = __expf(-fabsf(y));
    float sp = __logf(1.0f + t2);
    sp = (y > 0.0f) ? y + sp : sp;
    o2 = fminf(sp, 16.118095651f);
}

__device__ __forceinline__ int pbin(float p) {
    int b = (int)(p * (float)NBIN);
    return min(max(b, 0), NBIN - 1);
}

// Wave-parallel descending k-th-largest bin search over a histogram.
__device__ __forceinline__ bool wave_find(const int* __restrict__ h, int nbins, int k,
                                          int* bin_out, int* rank_out) {
    const int lane = threadIdx.x & 63;
    const int CH = nbins >> 6;
    const int topStart = nbins - 1 - lane * CH;
    int s = 0;
    for (int b = 0; b < CH; ++b) s += h[topStart - b];
    int incl = s;
    for (int off = 1; off < 64; off <<= 1) {
        int v = __shfl_up(incl, off, 64);
        if (lane >= off) incl += v;
    }
    int before = incl - s;
    if (before < k && k <= incl) {
        int c = before;
        for (int b = 0; b < CH; ++b) {
            int hb = h[topStart - b];
            c += hb;
            if (c >= k) { *bin_out = topStart - b; *rank_out = k - (c - hb); return true; }
        }
    }
    return false;
}

// ---------------- fat pass: all 12 loads in flight, zero global atomics -----
__global__ void __launch_bounds__(256, 4)
k_scan1(const float* __restrict__ outputs, const float* __restrict__ labels,
        const float* __restrict__ tmask, const float* __restrict__ gd,
        float* __restrict__ part) {
    __shared__ int lc[NBIN];
    __shared__ float l1[NBIN], l2[NBIN];
    __shared__ float rf[4][4];
    __shared__ int ri[4][2];
    const int t = threadIdx.x, n = blockIdx.y, lane = t & 63, wid = t >> 6;
    if (t < NBIN) { lc[t] = 0; l1[t] = 0.f; l2[t] = 0.f; }
    __syncthreads();
    const float4* P  = (const float4*)(outputs + (size_t)n * 2 * HWSZ);
    const float4* Th = P + NF4;
    const float4* G  = (const float4*)(labels + (size_t)n * 2 * HWSZ);
    const float4* Gt = G + NF4;
    const float4* T  = (const float4*)(tmask + (size_t)n * HWSZ);
    const float4* D  = (const float4*)(gd + (size_t)n * HWSZ);
    const int i4a = blockIdx.x * 512 + t, i4b = i4a + 256;
    // issue ALL 12 loads before any use (needs the launch_bounds VGPR release)
    float4 pA = P[i4a],  pB = P[i4b];
    float4 tA = Th[i4a], tB = Th[i4b];
    float4 gA = G[i4a],  gB = G[i4b];
    float4 qA = Gt[i4a], qB = Gt[i4b];
    float4 mA = T[i4a],  mB = T[i4b];
    float4 dA = D[i4a],  dB = D[i4b];
    float s3 = 0.f, s4 = 0.f, p1 = 0.f, p2 = 0.f;
    int cp = 0, cn = 0;
    auto proc = [&](const float4& p, const float4& th, const float4& g, const float4& q,
                    const float4& m, const float4& d) {
        const float* pp = (const float*)&p;  const float* tt = (const float*)&th;
        const float* gg = (const float*)&g;  const float* qq = (const float*)&q;
        const float* mm = (const float*)&m;  const float* dd = (const float*)&d;
#pragma unroll
        for (int e = 0; e < 4; ++e) {
            float pv = pp[e], tv = tt[e], gv = gg[e], qv = qq[e], mv = mm[e], dv = dd[e];
            s3 += fabsf(tv - qv) * dv;
            s4 += dv;
            bool msk = mv > 0.5f, tc = gv > 0.5f;
            if (msk) {
                float o1, o2; bce_pair(pv, tv, tc, o1, o2);
                if (tc) { p1 += o1; p2 += o2; cp++; }
                else {
                    cn++;
                    int b = pbin(pv);
                    atomicAdd(&lc[b], 1);
                    atomicAdd(&l1[b], o1);
                    atomicAdd(&l2[b], o2);
                }
            }
        }
    };
    proc(pA, tA, gA, qA, mA, dA);
    proc(pB, tB, gB, qB, mB, dB);
    for (int off = 32; off; off >>= 1) {
        p1 += __shfl_down(p1, off, 64);
        p2 += __shfl_down(p2, off, 64);
        s3 += __shfl_down(s3, off, 64);
        s4 += __shfl_down(s4, off, 64);
        cp += __shfl_down(cp, off, 64);
        cn += __shfl_down(cn, off, 64);
    }
    if (!lane) {
        rf[wid][0] = p1; rf[wid][1] = p2; rf[wid][2] = s3; rf[wid][3] = s4;
        ri[wid][0] = cp; ri[wid][1] = cn;
    }
    __syncthreads();
    float* slice = part + (size_t)(n * SBPS + blockIdx.x) * SLW;
    int* slice_i = (int*)slice;
    if (t < NBIN) {
        slice_i[t]            = lc[t];
        slice[NBIN + t]       = l1[t];
        slice[2 * NBIN + t]   = l2[t];
    }
    if (!t) {
        slice_i[3 * NBIN + 0] = ri[0][0] + ri[1][0] + ri[2][0] + ri[3][0];  // cp
        slice_i[3 * NBIN + 1] = ri[0][1] + ri[1][1] + ri[2][1] + ri[3][1];  // cn
        slice[3 * NBIN + 2]   = rf[0][0] + rf[1][0] + rf[2][0] + rf[3][0];  // p1
        slice[3 * NBIN + 3]   = rf[0][1] + rf[1][1] + rf[2][1] + rf[3][1];  // p2
        slice[3 * NBIN + 4]   = rf[0][2] + rf[1][2] + rf[2][2] + rf[3][2];  // s3
        slice[3 * NBIN + 5]   = rf[0][3] + rf[1][3] + rf[2][3] + rf[3][3];  // s4
    }
}

// ---------------- per-sample: reduce partials + select + suffix sums --------
__global__ void k_sel1(const float* __restrict__ part,
                       int* __restrict__ mode, int* __restrict__ b1o, int* __restrict__ k1o,
                       int* __restrict__ poss,
                       double* __restrict__ psum, double* __restrict__ ab1,
                       double* __restrict__ ab2, int* __restrict__ abc,
                       double* __restrict__ s3s, double* __restrict__ s4s) {
    __shared__ int lc[NBIN];
    __shared__ float l1[NBIN], l2[NBIN];
    __shared__ double sdr[4][4];
    __shared__ int sir[4][2];
    __shared__ double rda[4], rdb[4];
    __shared__ int ric[4];
    __shared__ int sb1, sk1, s_md, s_k;
    const int n = blockIdx.x, t = threadIdx.x, lane = t & 63, wid = t >> 6;
    const float* base = part + (size_t)n * SBPS * SLW;
    // ---- scalar reduction over SBPS block slices
    double p1 = 0.0, p2 = 0.0, s3 = 0.0, s4 = 0.0;
    int cp = 0, cn = 0;
    if (t < SBPS) {
        const float* sl = base + (size_t)t * SLW;
        const int* sli = (const int*)sl;
        cp = sli[3 * NBIN + 0]; cn = sli[3 * NBIN + 1];
        p1 = (double)sl[3 * NBIN + 2]; p2 = (double)sl[3 * NBIN + 3];
        s3 = (double)sl[3 * NBIN + 4]; s4 = (double)sl[3 * NBIN + 5];
    }
    for (int off = 32; off; off >>= 1) {
        p1 += __shfl_down(p1, off, 64);
        p2 += __shfl_down(p2, off, 64);
        s3 += __shfl_down(s3, off, 64);
        s4 += __shfl_down(s4, off, 64);
        cp += __shfl_down(cp, off, 64);
        cn += __shfl_down(cn, off, 64);
    }
    if (!lane) {
        sdr[wid][0] = p1; sdr[wid][1] = p2; sdr[wid][2] = s3; sdr[wid][3] = s4;
        sir[wid][0] = cp; sir[wid][1] = cn;
    }
    // ---- zero LDS histogram for two-half merge
    if (t < NBIN) { lc[t] = 0; l1[t] = 0.f; l2[t] = 0.f; }
    __syncthreads();
    if (!t) {
        int pos = sir[0][0] + sir[1][0] + sir[2][0] + sir[3][0];
        int neg = sir[0][1] + sir[1][1] + sir[2][1] + sir[3][1];
        int k = pos * 3; if (k > neg) k = neg;
        int md = (pos == 0) ? 2 : ((k == 0) ? 1 : 0);
        mode[n] = md;
        poss[n] = pos;
        psum[n * 2 + 0] = sdr[0][0] + sdr[1][0] + sdr[2][0] + sdr[3][0];
        psum[n * 2 + 1] = sdr[0][1] + sdr[1][1] + sdr[2][1] + sdr[3][1];
        s3s[n] = sdr[0][2] + sdr[1][2] + sdr[2][2] + sdr[3][2];
        s4s[n] = sdr[0][3] + sdr[1][3] + sdr[2][3] + sdr[3][3];
        s_md = md; s_k = k;
    }
    __syncthreads();
    const int md = s_md, k = s_k;
    if (md == 1) { if (!t) { ab1[n] = 0.0; ab2[n] = 0.0; abc[n] = 0; } return; }
    // ---- histogram reduction: both thread-halves cover half the slices each
    {
        const int bin = t & (NBIN - 1);
        const int j0 = (t < NBIN) ? 0 : SBPS / 2;
        const int j1 = (t < NBIN) ? SBPS / 2 : SBPS;
        int c = 0; float a = 0.f, b = 0.f;
        for (int j = j0; j < j1; ++j) {
            const float* sl = base + (size_t)j * SLW;
            c += ((const int*)sl)[bin];
            a += sl[NBIN + bin];
            b += sl[2 * NBIN + bin];
        }
        atomicAdd(&lc[bin], c);
        atomicAdd(&l1[bin], a);
        atomicAdd(&l2[bin], b);
    }
    __syncthreads();
    int B = -1;
    if (md == 0) {
        if (t < 64) { int bin, r; if (wave_find(lc, NBIN, k, &bin, &r)) { sb1 = bin; sk1 = r; } }
        __syncthreads();
        B = sb1;
        if (!t) { b1o[n] = sb1; k1o[n] = sk1; }
    }
    double a1 = 0.0, a2 = 0.0; int ac = 0;
    if (t < NBIN && t > B) { a1 = (double)l1[t]; a2 = (double)l2[t]; ac = lc[t]; }
    for (int off = 32; off; off >>= 1) {
        a1 += __shfl_down(a1, off, 64);
        a2 += __shfl_down(a2, off, 64);
        ac += __shfl_down(ac, off, 64);
    }
    if (!lane) { rda[wid] = a1; rdb[wid] = a2; ric[wid] = ac; }
    __syncthreads();
    if (!t) {
        ab1[n] = rda[0] + rda[1] + rda[2] + rda[3];
        ab2[n] = rdb[0] + rdb[1] + rdb[2] + rdb[3];
        abc[n] = ric[0] + ric[1] + ric[2] + ric[3];
    }
}

// ---------------- boundary-bin gather: LDS-staged, 1 atomic per block -------
__global__ void k_gather(const float* __restrict__ outputs, const float* __restrict__ labels,
                         const float* __restrict__ tmask,
                         const int* __restrict__ mode, const int* __restrict__ b1a,
                         int* __restrict__ cand_cnt, unsigned* __restrict__ ck,
                         float* __restrict__ cv1, float* __restrict__ cv2) {
    const int n = blockIdx.y;
    if (mode[n] != 0) return;
    const int b1n = b1a[n];
    __shared__ int lcnt, lbase;
    __shared__ unsigned lsk[BCAP];
    __shared__ float lv1[BCAP], lv2[BCAP];
    const int t = threadIdx.x;
    if (!t) lcnt = 0;
    __syncthreads();
    const float* bp = outputs + (size_t)n * 2 * HWSZ;
    const float4* P = (const float4*)bp;
    const float* Thp = bp + HWSZ;
    const float4* G = (const float4*)(labels + (size_t)n * 2 * HWSZ);
    const float4* T = (const float4*)(tmask + (size_t)n * HWSZ);
    const int stride = SBPS * 256;
    for (int i4 = blockIdx.x * 256 + t; i4 < NF4; i4 += stride) {
        float4 p = P[i4], g = G[i4], m = T[i4];
        const float* pp = (const float*)&p;
        const float* gg = (const float*)&g;
        const float* mm = (const float*)&m;
#pragma unroll
        for (int e = 0; e < 4; ++e) {
            bool cand = (gg[e] <= 0.5f) && (mm[e] > 0.5f) && (pbin(pp[e]) == b1n);
            if (cand) {
                float o1, o2; bce_pair(pp[e], Thp[4 * i4 + e], false, o1, o2);
                int idx = atomicAdd(&lcnt, 1);
                if (idx < BCAP) { lsk[idx] = fkey(pp[e]); lv1[idx] = o1; lv2[idx] = o2; }
                else {
                    int gi = atomicAdd(&cand_cnt[n * PADI], 1);   // rare overflow path
                    if (gi < CAP) { ck[n * CAP + gi] = fkey(pp[e]); cv1[n * CAP + gi] = o1; cv2[n * CAP + gi] = o2; }
                }
            }
        }
    }
    __syncthreads();
    const int cnt = min(lcnt, BCAP);
    if (!t && cnt) lbase = atomicAdd(&cand_cnt[n * PADI], cnt);
    __syncthreads();
    if (cnt) {
        const int bb = lbase;
        for (int i = t; i < cnt; i += 256) {
            int gi = bb + i;
            if (gi < CAP) { ck[n * CAP + gi] = lsk[i]; cv1[n * CAP + gi] = lv1[i]; cv2[n * CAP + gi] = lv2[i]; }
        }
    }
}

// ---------------- per-sample finalize (plain stores) ------------------------
__global__ void k_final(const float* __restrict__ outputs, const float* __restrict__ labels,
                        const float* __restrict__ tmask,
                        const int* __restrict__ mode, const int* __restrict__ b1a,
                        const int* __restrict__ k1a, const int* __restrict__ poss,
                        const int* __restrict__ cand_cnt, const unsigned* __restrict__ ck,
                        const float* __restrict__ cv1, const float* __restrict__ cv2,
                        const double* __restrict__ psum, const double* __restrict__ ab1,
                        const double* __restrict__ ab2, const int* __restrict__ abc,
                        double* __restrict__ res) {
    __shared__ unsigned sk[CAP];
    __shared__ float sv1[CAP], sv2[CAP];
    __shared__ int h[2048];
    __shared__ int sbh, srh, sbm, srm, sbl;
    __shared__ double rd[4][2];
    __shared__ int ri[4];
    const int n = blockIdx.x, t = threadIdx.x;
    const int md = mode[n];
    double f1r = 0.0, f2r = 0.0; int fcr = 0;
    if (md == 0) {
        const int k1 = k1a[n];
        const int cc = cand_cnt[n * PADI];
        float f1 = 0.f, f2 = 0.f; int fc = 0;
        if (cc <= CAP) {
            for (int i = t; i < cc; i += 256) {
                sk[i] = ck[n * CAP + i]; sv1[i] = cv1[n * CAP + i]; sv2[i] = cv2[n * CAP + i];
            }
            for (int i = t; i < 2048; i += 256) h[i] = 0;
            __syncthreads();
            for (int i = t; i < cc; i += 256) atomicAdd(&h[sk[i] >> 21], 1);
            __syncthreads();
            if (t < 64) { int b, r; if (wave_find(h, 2048, k1, &b, &r)) { sbh = b; srh = r; } }
            __syncthreads();
            const unsigned bh = (unsigned)sbh; const int r2 = srh;
            for (int i = t; i < 2048; i += 256) h[i] = 0;
            __syncthreads();
            for (int i = t; i < cc; i += 256)
                if ((sk[i] >> 21) == bh) atomicAdd(&h[(sk[i] >> 10) & 0x7FFu], 1);
            __syncthreads();
            if (t < 64) { int b, r; if (wave_find(h, 2048, r2, &b, &r)) { sbm = b; srm = r; } }
            __syncthreads();
            const unsigned bm = (unsigned)sbm; const int r3 = srm;
            for (int i = t; i < 1024; i += 256) h[i] = 0;
            __syncthreads();
            for (int i = t; i < cc; i += 256)
                if ((sk[i] >> 10) == ((bh << 11) | bm)) atomicAdd(&h[sk[i] & 0x3FFu], 1);
            __syncthreads();
            if (t < 64) { int b, r; if (wave_find(h, 1024, r3, &b, &r)) sbl = b; }
            __syncthreads();
            const unsigned thr_key = (bh << 21) | (bm << 10) | (unsigned)sbl;
            for (int i = t; i < cc; i += 256)
                if (sk[i] >= thr_key) { f1 += sv1[i]; f2 += sv2[i]; fc++; }
        } else {
            // slow path: rescan boundary bin from global (general insurance)
            const int b1n = b1a[n];
            const float* Pp = outputs + (size_t)n * 2 * HWSZ;
            const float* Thp = Pp + HWSZ;
            const float* Gp = labels + (size_t)n * 2 * HWSZ;
            const float* Tp = tmask + (size_t)n * HWSZ;
            for (int i = t; i < 2048; i += 256) h[i] = 0;
            __syncthreads();
            for (int i = t; i < HWSZ; i += 256) {
                float pv = Pp[i];
                if (Gp[i] <= 0.5f && Tp[i] > 0.5f && pbin(pv) == b1n)
                    atomicAdd(&h[fkey(pv) >> 21], 1);
            }
            __syncthreads();
            if (t < 64) { int b, r; if (wave_find(h, 2048, k1, &b, &r)) { sbh = b; srh = r; } }
            __syncthreads();
            const unsigned bh = (unsigned)sbh; const int r2 = srh;
            for (int i = t; i < 2048; i += 256) h[i] = 0;
            __syncthreads();
            for (int i = t; i < HWSZ; i += 256) {
                float pv = Pp[i]; unsigned key = fkey(pv);
                if (Gp[i] <= 0.5f && Tp[i] > 0.5f && pbin(pv) == b1n && (key >> 21) == bh)
                    atomicAdd(&h[(key >> 10) & 0x7FFu], 1);
            }
            __syncthreads();
            if (t < 64) { int b, r; if (wave_find(h, 2048, r2, &b, &r)) { sbm = b; srm = r; } }
            __syncthreads();
            const unsigned bm = (unsigned)sbm; const int r3 = srm;
            for (int i = t; i < 1024; i += 256) h[i] = 0;
            __syncthreads();
            for (int i = t; i < HWSZ; i += 256) {
                float pv = Pp[i]; unsigned key = fkey(pv);
                if (Gp[i] <= 0.5f && Tp[i] > 0.5f && pbin(pv) == b1n && (key >> 10) == ((bh << 11) | bm))
                    atomicAdd(&h[key & 0x3FFu], 1);
            }
            __syncthreads();
            if (t < 64) { int b, r; if (wave_find(h, 1024, r3, &b, &r)) sbl = b; }
            __syncthreads();
            const unsigned thr_key = (bh << 21) | (bm << 10) | (unsigned)sbl;
            for (int i = t; i < HWSZ; i += 256) {
                float pv = Pp[i];
                if (Gp[i] <= 0.5f && Tp[i] > 0.5f && pbin(pv) == b1n && fkey(pv) >= thr_key) {
                    float b1v, b2v; bce_pair(pv, Thp[i], false, b1v, b2v);
                    f1 += b1v; f2 += b2v; fc++;
                }
            }
        }
        double v0 = f1, v1 = f2;
        for (int off = 32; off; off >>= 1) {
            v0 += __shfl_down(v0, off, 64);
            v1 += __shfl_down(v1, off, 64);
            fc += __shfl_down(fc, off, 64);
        }
        const int lane = t & 63, wid = t >> 6;
        if (!lane) { rd[wid][0] = v0; rd[wid][1] = v1; ri[wid] = fc; }
        __syncthreads();
        if (!t) {
            f1r = rd[0][0] + rd[1][0] + rd[2][0] + rd[3][0];
            f2r = rd[0][1] + rd[1][1] + rd[2][1] + rd[3][1];
            fcr = ri[0] + ri[1] + ri[2] + ri[3];
        }
    }
    if (!t) {
        res[n * 3 + 0] = psum[n * 2 + 0] + ab1[n] + f1r;
        res[n * 3 + 1] = psum[n * 2 + 1] + ab2[n] + f2r;
        res[n * 3 + 2] = (double)poss[n] + (double)abc[n] + (double)fcr;
    }
}

__global__ void k_fin(const double* __restrict__ res, const double* __restrict__ s3s,
                      const double* __restrict__ s4s, float* __restrict__ out) {
    if (threadIdx.x != 0 || blockIdx.x != 0) return;
    double A = 0.0, Bb = 0.0, C = 0.0, S3 = 0.0, S4 = 0.0;
    for (int n = 0; n < NS; ++n) {
        A += res[n * 3 + 0]; Bb += res[n * 3 + 1]; C += res[n * 3 + 2];
        S3 += s3s[n]; S4 += s4s[n];
    }
    double lp = (C > 0.0) ? A / C : 0.0;
    double lb = (C > 0.0) ? Bb / C : 0.0;
    double lt = S3 / (S4 + 1e-6);
    out[0] = (float)(lp + lb + 10.0 * lt);
    out[1] = (float)lp;
    out[2] = (float)lb;
    out[3] = (float)lt;
}

extern "C" void kernel_launch(void* const* d_in, const int* in_sizes, int n_in,
                              void* d_out, int out_size, void* d_ws, size_t ws_size,
                              hipStream_t stream) {
    const float* outputs = (const float*)d_in[0];
    const float* labels  = (const float*)d_in[1];
    const float* tmask   = (const float*)d_in[2];
    const float* gd      = (const float*)d_in[3];
    float* out = (float*)d_out;

    char* ws = (char*)d_ws;
    double* s3s   = (double*)ws;                 // NS
    double* s4s   = s3s + NS;                    // NS
    double* psum  = s4s + NS;                    // NS*2
    double* ab1   = psum + NS * 2;               // NS
    double* ab2   = ab1 + NS;                    // NS
    double* res   = ab2 + NS;                    // NS*3
    int* abc      = (int*)(res + NS * 3);        // NS
    int* mode     = abc + NS;                    // NS
    int* b1       = mode + NS;                   // NS
    int* k1       = b1 + NS;                     // NS
    int* poss     = k1 + NS;                     // NS
    int* cand_cnt = poss + NS;                   // NS*PADI (padded counters)
    float* part   = (float*)(cand_cnt + NS * PADI);  // NS*SBPS*SLW (fully written)
    unsigned* ck  = (unsigned*)(part + (size_t)NS * SBPS * SLW);  // NS*CAP
    float* cv1    = (float*)(ck + NS * CAP);
    float* cv2    = cv1 + NS * CAP;
    (void)cv2; (void)ws_size; (void)in_sizes; (void)n_in; (void)out_size;

    // only the padded counters need zeroing; everything else is overwritten
    hipMemsetAsync(cand_cnt, 0, NS * PADI * sizeof(int), stream);

    k_scan1<<<dim3(SBPS, NS), 256, 0, stream>>>(outputs, labels, tmask, gd, part);
    k_sel1<<<NS, 256, 0, stream>>>(part, mode, b1, k1, poss, psum, ab1, ab2, abc, s3s, s4s);
    k_gather<<<dim3(SBPS, NS), 256, 0, stream>>>(outputs, labels, tmask, mode, b1,
                                                 cand_cnt, ck, cv1, cv2);
    k_final<<<NS, 256, 0, stream>>>(outputs, labels, tmask, mode, b1, k1, poss, cand_cnt,
                                    ck, cv1, cv2, psum, ab1, ab2, abc, res);
    k_fin<<<1, 64, 0, stream>>>(res, s3s, s4s, out);
}

// Round 8
// 76.956 us; speedup vs baseline: 1.3317x; 1.3317x over previous
//
#include <hip/hip_runtime.h>
#include <math.h>
#include <stdint.h>

#define NS    16
#define HWSZ  409600
#define NF4   102400      // float4s per sample
#define NBIN  128
#define SLW   (3*NBIN + 8) // words per block slice: hist cnt/s1/s2 + 8 scalar slots
#define CAP   4096
#define BCAP  512         // per-block LDS candidate staging
#define SBPS  200         // blocks per sample (contiguous 512-float4 chunks)
#define PADI  32          // ints per sample for padded atomic counter (128 B)

typedef unsigned long long u64;

__device__ __forceinline__ unsigned fkey(float f) {
    unsigned u = __float_as_uint(f);
    if (u == 0x80000000u) u = 0u;                 // canonicalize -0
    return (u & 0x80000000u) ? ~u : (u | 0x80000000u);
}

// bce1: BCE on p; bce2: BCE on sigmoid(50(p-t)); both with 1e-7 clipping
__device__ __forceinline__ void bce_pair(float pv, float tv, bool tc, float& o1, float& o2) {
    float pc = fminf(fmaxf(pv, 1e-7f), 1.0f - 1e-7f);
    float a = tc ? pc : 1.0f - pc;
    o1 = -__logf(a);
    float x = 50.0f * (pv - tv);
    float y = tc ? -x : x;
    float t2 = __expf(-fabsf(y));
    float sp = __logf(1.0f + t2);
    sp = (y > 0.0f) ? y + sp : sp;
    o2 = fminf(sp, 16.118095651f);
}

__device__ __forceinline__ int pbin(float p) {
    int b = (int)(p * (float)NBIN);
    return min(max(b, 0), NBIN - 1);
}

// Wave-parallel descending k-th-largest bin search over a histogram.
__device__ __forceinline__ bool wave_find(const int* __restrict__ h, int nbins, int k,
                                          int* bin_out, int* rank_out) {
    const int lane = threadIdx.x & 63;
    const int CH = nbins >> 6;
    const int topStart = nbins - 1 - lane * CH;
    int s = 0;
    for (int b = 0; b < CH; ++b) s += h[topStart - b];
    int incl = s;
    for (int off = 1; off < 64; off <<= 1) {
        int v = __shfl_up(incl, off, 64);
        if (lane >= off) incl += v;
    }
    int before = incl - s;
    if (before < k && k <= incl) {
        int c = before;
        for (int b = 0; b < CH; ++b) {
            int hb = h[topStart - b];
            c += hb;
            if (c >= k) { *bin_out = topStart - b; *rank_out = k - (c - hb); return true; }
        }
    }
    return false;
}

// ---------------- fat pass: forced-MLP loads, zero global atomics -----------
__global__ void k_scan1(const float* __restrict__ outputs, const float* __restrict__ labels,
                        const float* __restrict__ tmask, const float* __restrict__ gd,
                        float* __restrict__ part) {
    __shared__ int lc[NBIN];
    __shared__ float l1[NBIN], l2[NBIN];
    __shared__ float rf[4][4];
    __shared__ int ri[4][2];
    const int t = threadIdx.x, n = blockIdx.y, lane = t & 63, wid = t >> 6;
    if (t < NBIN) { lc[t] = 0; l1[t] = 0.f; l2[t] = 0.f; }
    __syncthreads();
    const float4* P  = (const float4*)(outputs + (size_t)n * 2 * HWSZ);
    const float4* Th = P + NF4;
    const float4* G  = (const float4*)(labels + (size_t)n * 2 * HWSZ);
    const float4* Gt = G + NF4;
    const float4* T  = (const float4*)(tmask + (size_t)n * HWSZ);
    const float4* D  = (const float4*)(gd + (size_t)n * HWSZ);
    const int i4a = blockIdx.x * 512 + t, i4b = i4a + 256;
    // chunk-A loads first, then chunk-B; sched_barrier(0) forces ALL 12
    // global_load_dwordx4 to issue before any compute (true MLP per wave).
    float4 pA = P[i4a], tA = Th[i4a], gA = G[i4a], qA = Gt[i4a], mA = T[i4a], dA = D[i4a];
    float4 pB = P[i4b], tB = Th[i4b], gB = G[i4b], qB = Gt[i4b], mB = T[i4b], dB = D[i4b];
    __builtin_amdgcn_sched_barrier(0);
    float s3 = 0.f, s4 = 0.f, p1 = 0.f, p2 = 0.f;
    int cp = 0, cn = 0;
    auto proc = [&](const float4& p, const float4& th, const float4& g, const float4& q,
                    const float4& m, const float4& d) {
        const float* pp = (const float*)&p;  const float* tt = (const float*)&th;
        const float* gg = (const float*)&g;  const float* qq = (const float*)&q;
        const float* mm = (const float*)&m;  const float* dd = (const float*)&d;
#pragma unroll
        for (int e = 0; e < 4; ++e) {
            float pv = pp[e], tv = tt[e], gv = gg[e], qv = qq[e], mv = mm[e], dv = dd[e];
            s3 += fabsf(tv - qv) * dv;
            s4 += dv;
            bool msk = mv > 0.5f, tc = gv > 0.5f;
            if (msk) {
                float o1, o2; bce_pair(pv, tv, tc, o1, o2);
                if (tc) { p1 += o1; p2 += o2; cp++; }
                else {
                    cn++;
                    int b = pbin(pv);
                    atomicAdd(&lc[b], 1);
                    atomicAdd(&l1[b], o1);
                    atomicAdd(&l2[b], o2);
                }
            }
        }
    };
    proc(pA, tA, gA, qA, mA, dA);
    proc(pB, tB, gB, qB, mB, dB);
    for (int off = 32; off; off >>= 1) {
        p1 += __shfl_down(p1, off, 64);
        p2 += __shfl_down(p2, off, 64);
        s3 += __shfl_down(s3, off, 64);
        s4 += __shfl_down(s4, off, 64);
        cp += __shfl_down(cp, off, 64);
        cn += __shfl_down(cn, off, 64);
    }
    if (!lane) {
        rf[wid][0] = p1; rf[wid][1] = p2; rf[wid][2] = s3; rf[wid][3] = s4;
        ri[wid][0] = cp; ri[wid][1] = cn;
    }
    __syncthreads();
    float* slice = part + (size_t)(n * SBPS + blockIdx.x) * SLW;
    int* slice_i = (int*)slice;
    if (t < NBIN) {
        slice_i[t]            = lc[t];
        slice[NBIN + t]       = l1[t];
        slice[2 * NBIN + t]   = l2[t];
    }
    if (!t) {
        slice_i[3 * NBIN + 0] = ri[0][0] + ri[1][0] + ri[2][0] + ri[3][0];  // cp
        slice_i[3 * NBIN + 1] = ri[0][1] + ri[1][1] + ri[2][1] + ri[3][1];  // cn
        slice[3 * NBIN + 2]   = rf[0][0] + rf[1][0] + rf[2][0] + rf[3][0];  // p1
        slice[3 * NBIN + 3]   = rf[0][1] + rf[1][1] + rf[2][1] + rf[3][1];  // p2
        slice[3 * NBIN + 4]   = rf[0][2] + rf[1][2] + rf[2][2] + rf[3][2];  // s3
        slice[3 * NBIN + 5]   = rf[0][3] + rf[1][3] + rf[2][3] + rf[3][3];  // s4
    }
}

// ---------------- per-sample: reduce partials + select + suffix sums --------
// modes: 0 = threshold in boundary bin; 1 = pos only; 2 = all masked; 3 = all neg+pos
__global__ void k_sel1(const float* __restrict__ part,
                       int* __restrict__ mode, int* __restrict__ b1o, int* __restrict__ k1o,
                       int* __restrict__ poss,
                       double* __restrict__ psum, double* __restrict__ ab1,
                       double* __restrict__ ab2, int* __restrict__ abc,
                       double* __restrict__ s3s, double* __restrict__ s4s) {
    __shared__ int lc[NBIN];
    __shared__ float l1[NBIN], l2[NBIN];
    __shared__ double sdr[4][4];
    __shared__ int sir[4][2];
    __shared__ double rda[4], rdb[4];
    __shared__ int ric[4];
    __shared__ int sb1, sk1, s_md, s_k;
    const int n = blockIdx.x, t = threadIdx.x, lane = t & 63, wid = t >> 6;
    const float* base = part + (size_t)n * SBPS * SLW;
    // ---- scalar reduction over SBPS block slices
    double p1 = 0.0, p2 = 0.0, s3 = 0.0, s4 = 0.0;
    int cp = 0, cn = 0;
    if (t < SBPS) {
        const float* sl = base + (size_t)t * SLW;
        const int* sli = (const int*)sl;
        cp = sli[3 * NBIN + 0]; cn = sli[3 * NBIN + 1];
        p1 = (double)sl[3 * NBIN + 2]; p2 = (double)sl[3 * NBIN + 3];
        s3 = (double)sl[3 * NBIN + 4]; s4 = (double)sl[3 * NBIN + 5];
    }
    for (int off = 32; off; off >>= 1) {
        p1 += __shfl_down(p1, off, 64);
        p2 += __shfl_down(p2, off, 64);
        s3 += __shfl_down(s3, off, 64);
        s4 += __shfl_down(s4, off, 64);
        cp += __shfl_down(cp, off, 64);
        cn += __shfl_down(cn, off, 64);
    }
    if (!lane) {
        sdr[wid][0] = p1; sdr[wid][1] = p2; sdr[wid][2] = s3; sdr[wid][3] = s4;
        sir[wid][0] = cp; sir[wid][1] = cn;
    }
    // ---- zero LDS histogram for two-half merge
    if (t < NBIN) { lc[t] = 0; l1[t] = 0.f; l2[t] = 0.f; }
    __syncthreads();
    if (!t) {
        int pos = sir[0][0] + sir[1][0] + sir[2][0] + sir[3][0];
        int neg = sir[0][1] + sir[1][1] + sir[2][1] + sir[3][1];
        int k = pos * 3; if (k > neg) k = neg;
        int md = (pos == 0) ? 2 : ((k == 0) ? 1 : ((k == neg) ? 3 : 0));
        mode[n] = md;
        poss[n] = pos;
        psum[n * 2 + 0] = sdr[0][0] + sdr[1][0] + sdr[2][0] + sdr[3][0];
        psum[n * 2 + 1] = sdr[0][1] + sdr[1][1] + sdr[2][1] + sdr[3][1];
        s3s[n] = sdr[0][2] + sdr[1][2] + sdr[2][2] + sdr[3][2];
        s4s[n] = sdr[0][3] + sdr[1][3] + sdr[2][3] + sdr[3][3];
        s_md = md; s_k = k;
    }
    __syncthreads();
    const int md = s_md, k = s_k;
    if (md == 1) { if (!t) { ab1[n] = 0.0; ab2[n] = 0.0; abc[n] = 0; } return; }
    // ---- histogram reduction: both thread-halves cover half the slices each
    {
        const int bin = t & (NBIN - 1);
        const int j0 = (t < NBIN) ? 0 : SBPS / 2;
        const int j1 = (t < NBIN) ? SBPS / 2 : SBPS;
        int c = 0; float a = 0.f, b = 0.f;
        for (int j = j0; j < j1; ++j) {
            const float* sl = base + (size_t)j * SLW;
            c += ((const int*)sl)[bin];
            a += sl[NBIN + bin];
            b += sl[2 * NBIN + bin];
        }
        atomicAdd(&lc[bin], c);
        atomicAdd(&l1[bin], a);
        atomicAdd(&l2[bin], b);
    }
    __syncthreads();
    int B = -1;   // md==2 or md==3: sum ALL bins
    if (md == 0) {
        if (t < 64) { int bin, r; if (wave_find(lc, NBIN, k, &bin, &r)) { sb1 = bin; sk1 = r; } }
        __syncthreads();
        B = sb1;
        if (!t) { b1o[n] = sb1; k1o[n] = sk1; }
    }
    double a1 = 0.0, a2 = 0.0; int ac = 0;
    if (t < NBIN && t > B) { a1 = (double)l1[t]; a2 = (double)l2[t]; ac = lc[t]; }
    for (int off = 32; off; off >>= 1) {
        a1 += __shfl_down(a1, off, 64);
        a2 += __shfl_down(a2, off, 64);
        ac += __shfl_down(ac, off, 64);
    }
    if (!lane) { rda[wid] = a1; rdb[wid] = a2; ric[wid] = ac; }
    __syncthreads();
    if (!t) {
        ab1[n] = rda[0] + rda[1] + rda[2] + rda[3];
        ab2[n] = rdb[0] + rdb[1] + rdb[2] + rdb[3];
        abc[n] = ric[0] + ric[1] + ric[2] + ric[3];
    }
}

// ---------------- boundary-bin gather: LDS-staged, 1 atomic per block -------
__global__ void k_gather(const float* __restrict__ outputs, const float* __restrict__ labels,
                         const float* __restrict__ tmask,
                         const int* __restrict__ mode, const int* __restrict__ b1a,
                         int* __restrict__ cand_cnt, unsigned* __restrict__ ck,
                         float* __restrict__ cv1, float* __restrict__ cv2) {
    const int n = blockIdx.y;
    if (mode[n] != 0) return;   // modes 1/2/3 need no boundary refinement
    const int b1n = b1a[n];
    __shared__ int lcnt, lbase;
    __shared__ unsigned lsk[BCAP];
    __shared__ float lv1[BCAP], lv2[BCAP];
    const int t = threadIdx.x;
    if (!t) lcnt = 0;
    __syncthreads();
    const float* bp = outputs + (size_t)n * 2 * HWSZ;
    const float4* P = (const float4*)bp;
    const float* Thp = bp + HWSZ;
    const float4* G = (const float4*)(labels + (size_t)n * 2 * HWSZ);
    const float4* T = (const float4*)(tmask + (size_t)n * HWSZ);
    const int stride = SBPS * 256;
    for (int i4 = blockIdx.x * 256 + t; i4 < NF4; i4 += stride) {
        float4 p = P[i4], g = G[i4], m = T[i4];
        const float* pp = (const float*)&p;
        const float* gg = (const float*)&g;
        const float* mm = (const float*)&m;
#pragma unroll
        for (int e = 0; e < 4; ++e) {
            bool cand = (gg[e] <= 0.5f) && (mm[e] > 0.5f) && (pbin(pp[e]) == b1n);
            if (cand) {
                float o1, o2; bce_pair(pp[e], Thp[4 * i4 + e], false, o1, o2);
                int idx = atomicAdd(&lcnt, 1);
                if (idx < BCAP) { lsk[idx] = fkey(pp[e]); lv1[idx] = o1; lv2[idx] = o2; }
                else {
                    int gi = atomicAdd(&cand_cnt[n * PADI], 1);   // rare overflow path
                    if (gi < CAP) { ck[n * CAP + gi] = fkey(pp[e]); cv1[n * CAP + gi] = o1; cv2[n * CAP + gi] = o2; }
                }
            }
        }
    }
    __syncthreads();
    const int cnt = min(lcnt, BCAP);
    if (!t && cnt) lbase = atomicAdd(&cand_cnt[n * PADI], cnt);
    __syncthreads();
    if (cnt) {
        const int bb = lbase;
        for (int i = t; i < cnt; i += 256) {
            int gi = bb + i;
            if (gi < CAP) { ck[n * CAP + gi] = lsk[i]; cv1[n * CAP + gi] = lv1[i]; cv2[n * CAP + gi] = lv2[i]; }
        }
    }
}

// ---------------- per-sample finalize (plain stores) ------------------------
__global__ void k_final(const float* __restrict__ outputs, const float* __restrict__ labels,
                        const float* __restrict__ tmask,
                        const int* __restrict__ mode, const int* __restrict__ b1a,
                        const int* __restrict__ k1a, const int* __restrict__ poss,
                        const int* __restrict__ cand_cnt, const unsigned* __restrict__ ck,
                        const float* __restrict__ cv1, const float* __restrict__ cv2,
                        const double* __restrict__ psum, const double* __restrict__ ab1,
                        const double* __restrict__ ab2, const int* __restrict__ abc,
                        double* __restrict__ res) {
    __shared__ unsigned sk[CAP];
    __shared__ float sv1[CAP], sv2[CAP];
    __shared__ int h[2048];
    __shared__ int sbh, srh, sbm, srm, sbl;
    __shared__ double rd[4][2];
    __shared__ int ri[4];
    const int n = blockIdx.x, t = threadIdx.x;
    const int md = mode[n];
    double f1r = 0.0, f2r = 0.0; int fcr = 0;
    if (md == 0) {
        const int k1 = k1a[n];
        const int cc = cand_cnt[n * PADI];
        float f1 = 0.f, f2 = 0.f; int fc = 0;
        if (cc <= CAP) {
            for (int i = t; i < cc; i += 256) {
                sk[i] = ck[n * CAP + i]; sv1[i] = cv1[n * CAP + i]; sv2[i] = cv2[n * CAP + i];
            }
            for (int i = t; i < 2048; i += 256) h[i] = 0;
            __syncthreads();
            for (int i = t; i < cc; i += 256) atomicAdd(&h[sk[i] >> 21], 1);
            __syncthreads();
            if (t < 64) { int b, r; if (wave_find(h, 2048, k1, &b, &r)) { sbh = b; srh = r; } }
            __syncthreads();
            const unsigned bh = (unsigned)sbh; const int r2 = srh;
            for (int i = t; i < 2048; i += 256) h[i] = 0;
            __syncthreads();
            for (int i = t; i < cc; i += 256)
                if ((sk[i] >> 21) == bh) atomicAdd(&h[(sk[i] >> 10) & 0x7FFu], 1);
            __syncthreads();
            if (t < 64) { int b, r; if (wave_find(h, 2048, r2, &b, &r)) { sbm = b; srm = r; } }
            __syncthreads();
            const unsigned bm = (unsigned)sbm; const int r3 = srm;
            for (int i = t; i < 1024; i += 256) h[i] = 0;
            __syncthreads();
            for (int i = t; i < cc; i += 256)
                if ((sk[i] >> 10) == ((bh << 11) | bm)) atomicAdd(&h[sk[i] & 0x3FFu], 1);
            __syncthreads();
            if (t < 64) { int b, r; if (wave_find(h, 1024, r3, &b, &r)) sbl = b; }
            __syncthreads();
            const unsigned thr_key = (bh << 21) | (bm << 10) | (unsigned)sbl;
            for (int i = t; i < cc; i += 256)
                if (sk[i] >= thr_key) { f1 += sv1[i]; f2 += sv2[i]; fc++; }
        } else {
            // slow path: rescan boundary bin from global (general insurance)
            const int b1n = b1a[n];
            const float* Pp = outputs + (size_t)n * 2 * HWSZ;
            const float* Thp = Pp + HWSZ;
            const float* Gp = labels + (size_t)n * 2 * HWSZ;
            const float* Tp = tmask + (size_t)n * HWSZ;
            for (int i = t; i < 2048; i += 256) h[i] = 0;
            __syncthreads();
            for (int i = t; i < HWSZ; i += 256) {
                float pv = Pp[i];
                if (Gp[i] <= 0.5f && Tp[i] > 0.5f && pbin(pv) == b1n)
                    atomicAdd(&h[fkey(pv) >> 21], 1);
            }
            __syncthreads();
            if (t < 64) { int b, r; if (wave_find(h, 2048, k1, &b, &r)) { sbh = b; srh = r; } }
            __syncthreads();
            const unsigned bh = (unsigned)sbh; const int r2 = srh;
            for (int i = t; i < 2048; i += 256) h[i] = 0;
            __syncthreads();
            for (int i = t; i < HWSZ; i += 256) {
                float pv = Pp[i]; unsigned key = fkey(pv);
                if (Gp[i] <= 0.5f && Tp[i] > 0.5f && pbin(pv) == b1n && (key >> 21) == bh)
                    atomicAdd(&h[(key >> 10) & 0x7FFu], 1);
            }
            __syncthreads();
            if (t < 64) { int b, r; if (wave_find(h, 2048, r2, &b, &r)) { sbm = b; srm = r; } }
            __syncthreads();
            const unsigned bm = (unsigned)sbm; const int r3 = srm;
            for (int i = t; i < 1024; i += 256) h[i] = 0;
            __syncthreads();
            for (int i = t; i < HWSZ; i += 256) {
                float pv = Pp[i]; unsigned key = fkey(pv);
                if (Gp[i] <= 0.5f && Tp[i] > 0.5f && pbin(pv) == b1n && (key >> 10) == ((bh << 11) | bm))
                    atomicAdd(&h[key & 0x3FFu], 1);
            }
            __syncthreads();
            if (t < 64) { int b, r; if (wave_find(h, 1024, r3, &b, &r)) sbl = b; }
            __syncthreads();
            const unsigned thr_key = (bh << 21) | (bm << 10) | (unsigned)sbl;
            for (int i = t; i < HWSZ; i += 256) {
                float pv = Pp[i];
                if (Gp[i] <= 0.5f && Tp[i] > 0.5f && pbin(pv) == b1n && fkey(pv) >= thr_key) {
                    float b1v, b2v; bce_pair(pv, Thp[i], false, b1v, b2v);
                    f1 += b1v; f2 += b2v; fc++;
                }
            }
        }
        double v0 = f1, v1 = f2;
        for (int off = 32; off; off >>= 1) {
            v0 += __shfl_down(v0, off, 64);
            v1 += __shfl_down(v1, off, 64);
            fc += __shfl_down(fc, off, 64);
        }
        const int lane = t & 63, wid = t >> 6;
        if (!lane) { rd[wid][0] = v0; rd[wid][1] = v1; ri[wid] = fc; }
        __syncthreads();
        if (!t) {
            f1r = rd[0][0] + rd[1][0] + rd[2][0] + rd[3][0];
            f2r = rd[0][1] + rd[1][1] + rd[2][1] + rd[3][1];
            fcr = ri[0] + ri[1] + ri[2] + ri[3];
        }
    }
    if (!t) {
        res[n * 3 + 0] = psum[n * 2 + 0] + ab1[n] + f1r;
        res[n * 3 + 1] = psum[n * 2 + 1] + ab2[n] + f2r;
        res[n * 3 + 2] = (double)poss[n] + (double)abc[n] + (double)fcr;
    }
}

__global__ void k_fin(const double* __restrict__ res, const double* __restrict__ s3s,
                      const double* __restrict__ s4s, float* __restrict__ out) {
    if (threadIdx.x != 0 || blockIdx.x != 0) return;
    double A = 0.0, Bb = 0.0, C = 0.0, S3 = 0.0, S4 = 0.0;
    for (int n = 0; n < NS; ++n) {
        A += res[n * 3 + 0]; Bb += res[n * 3 + 1]; C += res[n * 3 + 2];
        S3 += s3s[n]; S4 += s4s[n];
    }
    double lp = (C > 0.0) ? A / C : 0.0;
    double lb = (C > 0.0) ? Bb / C : 0.0;
    double lt = S3 / (S4 + 1e-6);
    out[0] = (float)(lp + lb + 10.0 * lt);
    out[1] = (float)lp;
    out[2] = (float)lb;
    out[3] = (float)lt;
}

extern "C" void kernel_launch(void* const* d_in, const int* in_sizes, int n_in,
                              void* d_out, int out_size, void* d_ws, size_t ws_size,
                              hipStream_t stream) {
    const float* outputs = (const float*)d_in[0];
    const float* labels  = (const float*)d_in[1];
    const float* tmask   = (const float*)d_in[2];
    const float* gd      = (const float*)d_in[3];
    float* out = (float*)d_out;

    char* ws = (char*)d_ws;
    double* s3s   = (double*)ws;                 // NS
    double* s4s   = s3s + NS;                    // NS
    double* psum  = s4s + NS;                    // NS*2
    double* ab1   = psum + NS * 2;               // NS
    double* ab2   = ab1 + NS;                    // NS
    double* res   = ab2 + NS;                    // NS*3
    int* abc      = (int*)(res + NS * 3);        // NS
    int* mode     = abc + NS;                    // NS
    int* b1       = mode + NS;                   // NS
    int* k1       = b1 + NS;                     // NS
    int* poss     = k1 + NS;                     // NS
    int* cand_cnt = poss + NS;                   // NS*PADI (padded counters)
    float* part   = (float*)(cand_cnt + NS * PADI);  // NS*SBPS*SLW (fully written)
    unsigned* ck  = (unsigned*)(part + (size_t)NS * SBPS * SLW);  // NS*CAP
    float* cv1    = (float*)(ck + NS * CAP);
    float* cv2    = cv1 + NS * CAP;
    (void)cv2; (void)ws_size; (void)in_sizes; (void)n_in; (void)out_size;

    // only the padded counters need zeroing; everything else is overwritten
    hipMemsetAsync(cand_cnt, 0, NS * PADI * sizeof(int), stream);

    k_scan1<<<dim3(SBPS, NS), 256, 0, stream>>>(outputs, labels, tmask, gd, part);
    k_sel1<<<NS, 256, 0, stream>>>(part, mode, b1, k1, poss, psum, ab1, ab2, abc, s3s, s4s);
    k_gather<<<dim3(SBPS, NS), 256, 0, stream>>>(outputs, labels, tmask, mode, b1,
                                                 cand_cnt, ck, cv1, cv2);
    k_final<<<NS, 256, 0, stream>>>(outputs, labels, tmask, mode, b1, k1, poss, cand_cnt,
                                    ck, cv1, cv2, psum, ab1, ab2, abc, res);
    k_fin<<<1, 64, 0, stream>>>(res, s3s, s4s, out);
}

// Round 9
// 55.565 us; speedup vs baseline: 1.8443x; 1.3850x over previous
//
#include <hip/hip_runtime.h>
#include <math.h>
#include <stdint.h>

#define NS    16
#define HWSZ  409600
#define NF4   102400      // float4s per sample
#define NBIN  128
#define SLW   (3*NBIN + 8) // words per block slice: hist cnt/s1/s2 + 8 scalar slots
#define CAP   4096
#define BCAP  512         // per-block LDS candidate staging
#define SBPS  200         // blocks per sample (contiguous 512-float4 chunks)
#define PADI  32          // ints per sample for padded atomic counter (128 B)

typedef unsigned long long u64;
typedef float f32x4 __attribute__((ext_vector_type(4)));

__device__ __forceinline__ unsigned fkey(float f) {
    unsigned u = __float_as_uint(f);
    if (u == 0x80000000u) u = 0u;                 // canonicalize -0
    return (u & 0x80000000u) ? ~u : (u | 0x80000000u);
}

// bce1: BCE on p; bce2: BCE on sigmoid(50(p-t)); both with 1e-7 clipping
__device__ __forceinline__ void bce_pair(float pv, float tv, bool tc, float& o1, float& o2) {
    float pc = fminf(fmaxf(pv, 1e-7f), 1.0f - 1e-7f);
    float a = tc ? pc : 1.0f - pc;
    o1 = -__logf(a);
    float x = 50.0f * (pv - tv);
    float y = tc ? -x : x;
    float t2 = __expf(-fabsf(y));
    float sp = __logf(1.0f + t2);
    sp = (y > 0.0f) ? y + sp : sp;
    o2 = fminf(sp, 16.118095651f);
}

__device__ __forceinline__ int pbin(float p) {
    int b = (int)(p * (float)NBIN);
    return min(max(b, 0), NBIN - 1);
}

// Wave-parallel descending k-th-largest bin search over a histogram.
__device__ __forceinline__ bool wave_find(const int* __restrict__ h, int nbins, int k,
                                          int* bin_out, int* rank_out) {
    const int lane = threadIdx.x & 63;
    const int CH = nbins >> 6;
    const int topStart = nbins - 1 - lane * CH;
    int s = 0;
    for (int b = 0; b < CH; ++b) s += h[topStart - b];
    int incl = s;
    for (int off = 1; off < 64; off <<= 1) {
        int v = __shfl_up(incl, off, 64);
        if (lane >= off) incl += v;
    }
    int before = incl - s;
    if (before < k && k <= incl) {
        int c = before;
        for (int b = 0; b < CH; ++b) {
            int hb = h[topStart - b];
            c += hb;
            if (c >= k) { *bin_out = topStart - b; *rank_out = k - (c - hb); return true; }
        }
    }
    return false;
}

#define GLOAD(dst, addr) \
    asm volatile("global_load_dwordx4 %0, %1, off" : "=v"(dst) : "v"(addr))

// ---------------- fat pass: asm-forced 12-deep load batch -------------------
__global__ void k_scan1(const float* __restrict__ outputs, const float* __restrict__ labels,
                        const float* __restrict__ tmask, const float* __restrict__ gd,
                        float* __restrict__ part) {
    __shared__ int lc[NBIN];
    __shared__ float l1[NBIN], l2[NBIN];
    __shared__ float rf[4][4];
    __shared__ int ri[4][2];
    const int t = threadIdx.x, n = blockIdx.y, lane = t & 63, wid = t >> 6;
    if (t < NBIN) { lc[t] = 0; l1[t] = 0.f; l2[t] = 0.f; }
    __syncthreads();
    const f32x4* P  = (const f32x4*)(outputs + (size_t)n * 2 * HWSZ);
    const f32x4* Th = P + NF4;
    const f32x4* G  = (const f32x4*)(labels + (size_t)n * 2 * HWSZ);
    const f32x4* Gt = G + NF4;
    const f32x4* T  = (const f32x4*)(tmask + (size_t)n * HWSZ);
    const f32x4* D  = (const f32x4*)(gd + (size_t)n * HWSZ);
    const int i4a = blockIdx.x * 512 + t, i4b = i4a + 256;
    // 12 volatile asm loads: mutually ordered, all issue before the waitcnt.
    f32x4 pA, tA, gA, qA, mA, dA, pB, tB, gB, qB, mB, dB;
    GLOAD(pA, P + i4a);  GLOAD(tA, Th + i4a); GLOAD(gA, G + i4a);
    GLOAD(qA, Gt + i4a); GLOAD(mA, T + i4a);  GLOAD(dA, D + i4a);
    GLOAD(pB, P + i4b);  GLOAD(tB, Th + i4b); GLOAD(gB, G + i4b);
    GLOAD(qB, Gt + i4b); GLOAD(mB, T + i4b);  GLOAD(dB, D + i4b);
    asm volatile("s_waitcnt vmcnt(0)"
                 : "+v"(pA), "+v"(tA), "+v"(gA), "+v"(qA), "+v"(mA), "+v"(dA),
                   "+v"(pB), "+v"(tB), "+v"(gB), "+v"(qB), "+v"(mB), "+v"(dB)
                 :: "memory");
    __builtin_amdgcn_sched_barrier(0);
    float s3 = 0.f, s4 = 0.f, p1 = 0.f, p2 = 0.f;
    int cp = 0, cn = 0;
    auto proc = [&](const f32x4& p, const f32x4& th, const f32x4& g, const f32x4& q,
                    const f32x4& m, const f32x4& d) {
#pragma unroll
        for (int e = 0; e < 4; ++e) {
            float pv = p[e], tv = th[e], gv = g[e], qv = q[e], mv = m[e], dv = d[e];
            s3 += fabsf(tv - qv) * dv;
            s4 += dv;
            bool msk = mv > 0.5f, tc = gv > 0.5f;
            if (msk) {
                float o1, o2; bce_pair(pv, tv, tc, o1, o2);
                if (tc) { p1 += o1; p2 += o2; cp++; }
                else {
                    cn++;
                    int b = pbin(pv);
                    atomicAdd(&lc[b], 1);
                    atomicAdd(&l1[b], o1);
                    atomicAdd(&l2[b], o2);
                }
            }
        }
    };
    proc(pA, tA, gA, qA, mA, dA);
    proc(pB, tB, gB, qB, mB, dB);
    for (int off = 32; off; off >>= 1) {
        p1 += __shfl_down(p1, off, 64);
        p2 += __shfl_down(p2, off, 64);
        s3 += __shfl_down(s3, off, 64);
        s4 += __shfl_down(s4, off, 64);
        cp += __shfl_down(cp, off, 64);
        cn += __shfl_down(cn, off, 64);
    }
    if (!lane) {
        rf[wid][0] = p1; rf[wid][1] = p2; rf[wid][2] = s3; rf[wid][3] = s4;
        ri[wid][0] = cp; ri[wid][1] = cn;
    }
    __syncthreads();
    float* slice = part + (size_t)(n * SBPS + blockIdx.x) * SLW;
    int* slice_i = (int*)slice;
    if (t < NBIN) {
        slice_i[t]            = lc[t];
        slice[NBIN + t]       = l1[t];
        slice[2 * NBIN + t]   = l2[t];
    }
    if (!t) {
        slice_i[3 * NBIN + 0] = ri[0][0] + ri[1][0] + ri[2][0] + ri[3][0];  // cp
        slice_i[3 * NBIN + 1] = ri[0][1] + ri[1][1] + ri[2][1] + ri[3][1];  // cn
        slice[3 * NBIN + 2]   = rf[0][0] + rf[1][0] + rf[2][0] + rf[3][0];  // p1
        slice[3 * NBIN + 3]   = rf[0][1] + rf[1][1] + rf[2][1] + rf[3][1];  // p2
        slice[3 * NBIN + 4]   = rf[0][2] + rf[1][2] + rf[2][2] + rf[3][2];  // s3
        slice[3 * NBIN + 5]   = rf[0][3] + rf[1][3] + rf[2][3] + rf[3][3];  // s4
    }
}

// ---------------- per-sample: reduce partials + select + suffix sums --------
// modes: 0 = threshold in boundary bin; 1 = pos only; 2 = all masked; 3 = all neg+pos
// 1024 threads: 8-way split of the slice-reduction loop (25 slices per thread).
__global__ void k_sel1(const float* __restrict__ part,
                       int* __restrict__ mode, int* __restrict__ b1o, int* __restrict__ k1o,
                       int* __restrict__ poss,
                       double* __restrict__ psum, double* __restrict__ ab1,
                       double* __restrict__ ab2, int* __restrict__ abc,
                       double* __restrict__ s3s, double* __restrict__ s4s) {
    __shared__ int lc[NBIN];
    __shared__ float l1[NBIN], l2[NBIN];
    __shared__ double sdr[16][4];
    __shared__ int sir[16][2];
    __shared__ double rda[16], rdb[16];
    __shared__ int ric[16];
    __shared__ int sb1, sk1, s_md, s_k;
    const int n = blockIdx.x, t = threadIdx.x, lane = t & 63, wid = t >> 6;
    const float* base = part + (size_t)n * SBPS * SLW;
    // ---- scalar reduction over SBPS block slices
    double p1 = 0.0, p2 = 0.0, s3 = 0.0, s4 = 0.0;
    int cp = 0, cn = 0;
    if (t < SBPS) {
        const float* sl = base + (size_t)t * SLW;
        const int* sli = (const int*)sl;
        cp = sli[3 * NBIN + 0]; cn = sli[3 * NBIN + 1];
        p1 = (double)sl[3 * NBIN + 2]; p2 = (double)sl[3 * NBIN + 3];
        s3 = (double)sl[3 * NBIN + 4]; s4 = (double)sl[3 * NBIN + 5];
    }
    for (int off = 32; off; off >>= 1) {
        p1 += __shfl_down(p1, off, 64);
        p2 += __shfl_down(p2, off, 64);
        s3 += __shfl_down(s3, off, 64);
        s4 += __shfl_down(s4, off, 64);
        cp += __shfl_down(cp, off, 64);
        cn += __shfl_down(cn, off, 64);
    }
    if (!lane) {
        sdr[wid][0] = p1; sdr[wid][1] = p2; sdr[wid][2] = s3; sdr[wid][3] = s4;
        sir[wid][0] = cp; sir[wid][1] = cn;
    }
    if (t < NBIN) { lc[t] = 0; l1[t] = 0.f; l2[t] = 0.f; }
    __syncthreads();
    if (!t) {
        int pos = 0, neg = 0;
        double a = 0.0, b = 0.0, c = 0.0, d = 0.0;
        for (int w = 0; w < 16; ++w) {
            pos += sir[w][0]; neg += sir[w][1];
            a += sdr[w][0]; b += sdr[w][1]; c += sdr[w][2]; d += sdr[w][3];
        }
        int k = pos * 3; if (k > neg) k = neg;
        int md = (pos == 0) ? 2 : ((k == 0) ? 1 : ((k == neg) ? 3 : 0));
        mode[n] = md;
        poss[n] = pos;
        psum[n * 2 + 0] = a;
        psum[n * 2 + 1] = b;
        s3s[n] = c;
        s4s[n] = d;
        s_md = md; s_k = k;
    }
    __syncthreads();
    const int md = s_md, k = s_k;
    if (md == 1) { if (!t) { ab1[n] = 0.0; ab2[n] = 0.0; abc[n] = 0; } return; }
    // ---- histogram reduction: 8 thread-groups cover 25 slices each
    {
        const int bin = t & (NBIN - 1);
        const int grp = t >> 7;               // 0..7
        const int j0 = grp * (SBPS / 8);
        const int j1 = j0 + (SBPS / 8);
        int c = 0; float a = 0.f, b = 0.f;
        for (int j = j0; j < j1; ++j) {
            const float* sl = base + (size_t)j * SLW;
            c += ((const int*)sl)[bin];
            a += sl[NBIN + bin];
            b += sl[2 * NBIN + bin];
        }
        atomicAdd(&lc[bin], c);
        atomicAdd(&l1[bin], a);
        atomicAdd(&l2[bin], b);
    }
    __syncthreads();
    int B = -1;   // md==2 or md==3: sum ALL bins
    if (md == 0) {
        if (t < 64) { int bin, r; if (wave_find(lc, NBIN, k, &bin, &r)) { sb1 = bin; sk1 = r; } }
        __syncthreads();
        B = sb1;
        if (!t) { b1o[n] = sb1; k1o[n] = sk1; }
    }
    double a1 = 0.0, a2 = 0.0; int ac = 0;
    if (t < NBIN && t > B) { a1 = (double)l1[t]; a2 = (double)l2[t]; ac = lc[t]; }
    for (int off = 32; off; off >>= 1) {
        a1 += __shfl_down(a1, off, 64);
        a2 += __shfl_down(a2, off, 64);
        ac += __shfl_down(ac, off, 64);
    }
    if (!lane) { rda[wid] = a1; rdb[wid] = a2; ric[wid] = ac; }
    __syncthreads();
    if (!t) {
        double ra = 0.0, rb = 0.0; int rc = 0;
        for (int w = 0; w < 16; ++w) { ra += rda[w]; rb += rdb[w]; rc += ric[w]; }
        ab1[n] = ra; ab2[n] = rb; abc[n] = rc;
    }
}

// ---------------- boundary-bin gather: LDS-staged, 1 atomic per block -------
__global__ void k_gather(const float* __restrict__ outputs, const float* __restrict__ labels,
                         const float* __restrict__ tmask,
                         const int* __restrict__ mode, const int* __restrict__ b1a,
                         int* __restrict__ cand_cnt, unsigned* __restrict__ ck,
                         float* __restrict__ cv1, float* __restrict__ cv2) {
    const int n = blockIdx.y;
    if (mode[n] != 0) return;   // modes 1/2/3 need no boundary refinement
    const int b1n = b1a[n];
    __shared__ int lcnt, lbase;
    __shared__ unsigned lsk[BCAP];
    __shared__ float lv1[BCAP], lv2[BCAP];
    const int t = threadIdx.x;
    if (!t) lcnt = 0;
    __syncthreads();
    const float* bp = outputs + (size_t)n * 2 * HWSZ;
    const float4* P = (const float4*)bp;
    const float* Thp = bp + HWSZ;
    const float4* G = (const float4*)(labels + (size_t)n * 2 * HWSZ);
    const float4* T = (const float4*)(tmask + (size_t)n * HWSZ);
    const int stride = SBPS * 256;
    for (int i4 = blockIdx.x * 256 + t; i4 < NF4; i4 += stride) {
        float4 p = P[i4], g = G[i4], m = T[i4];
        const float* pp = (const float*)&p;
        const float* gg = (const float*)&g;
        const float* mm = (const float*)&m;
#pragma unroll
        for (int e = 0; e < 4; ++e) {
            bool cand = (gg[e] <= 0.5f) && (mm[e] > 0.5f) && (pbin(pp[e]) == b1n);
            if (cand) {
                float o1, o2; bce_pair(pp[e], Thp[4 * i4 + e], false, o1, o2);
                int idx = atomicAdd(&lcnt, 1);
                if (idx < BCAP) { lsk[idx] = fkey(pp[e]); lv1[idx] = o1; lv2[idx] = o2; }
                else {
                    int gi = atomicAdd(&cand_cnt[n * PADI], 1);   // rare overflow path
                    if (gi < CAP) { ck[n * CAP + gi] = fkey(pp[e]); cv1[n * CAP + gi] = o1; cv2[n * CAP + gi] = o2; }
                }
            }
        }
    }
    __syncthreads();
    const int cnt = min(lcnt, BCAP);
    if (!t && cnt) lbase = atomicAdd(&cand_cnt[n * PADI], cnt);
    __syncthreads();
    if (cnt) {
        const int bb = lbase;
        for (int i = t; i < cnt; i += 256) {
            int gi = bb + i;
            if (gi < CAP) { ck[n * CAP + gi] = lsk[i]; cv1[n * CAP + gi] = lv1[i]; cv2[n * CAP + gi] = lv2[i]; }
        }
    }
}

// ---------------- per-sample finalize (plain stores) ------------------------
__global__ void k_final(const float* __restrict__ outputs, const float* __restrict__ labels,
                        const float* __restrict__ tmask,
                        const int* __restrict__ mode, const int* __restrict__ b1a,
                        const int* __restrict__ k1a, const int* __restrict__ poss,
                        const int* __restrict__ cand_cnt, const unsigned* __restrict__ ck,
                        const float* __restrict__ cv1, const float* __restrict__ cv2,
                        const double* __restrict__ psum, const double* __restrict__ ab1,
                        const double* __restrict__ ab2, const int* __restrict__ abc,
                        double* __restrict__ res) {
    __shared__ unsigned sk[CAP];
    __shared__ float sv1[CAP], sv2[CAP];
    __shared__ int h[2048];
    __shared__ int sbh, srh, sbm, srm, sbl;
    __shared__ double rd[4][2];
    __shared__ int ri[4];
    const int n = blockIdx.x, t = threadIdx.x;
    const int md = mode[n];
    double f1r = 0.0, f2r = 0.0; int fcr = 0;
    if (md == 0) {
        const int k1 = k1a[n];
        const int cc = cand_cnt[n * PADI];
        float f1 = 0.f, f2 = 0.f; int fc = 0;
        if (cc <= CAP) {
            for (int i = t; i < cc; i += 256) {
                sk[i] = ck[n * CAP + i]; sv1[i] = cv1[n * CAP + i]; sv2[i] = cv2[n * CAP + i];
            }
            for (int i = t; i < 2048; i += 256) h[i] = 0;
            __syncthreads();
            for (int i = t; i < cc; i += 256) atomicAdd(&h[sk[i] >> 21], 1);
            __syncthreads();
            if (t < 64) { int b, r; if (wave_find(h, 2048, k1, &b, &r)) { sbh = b; srh = r; } }
            __syncthreads();
            const unsigned bh = (unsigned)sbh; const int r2 = srh;
            for (int i = t; i < 2048; i += 256) h[i] = 0;
            __syncthreads();
            for (int i = t; i < cc; i += 256)
                if ((sk[i] >> 21) == bh) atomicAdd(&h[(sk[i] >> 10) & 0x7FFu], 1);
            __syncthreads();
            if (t < 64) { int b, r; if (wave_find(h, 2048, r2, &b, &r)) { sbm = b; srm = r; } }
            __syncthreads();
            const unsigned bm = (unsigned)sbm; const int r3 = srm;
            for (int i = t; i < 1024; i += 256) h[i] = 0;
            __syncthreads();
            for (int i = t; i < cc; i += 256)
                if ((sk[i] >> 10) == ((bh << 11) | bm)) atomicAdd(&h[sk[i] & 0x3FFu], 1);
            __syncthreads();
            if (t < 64) { int b, r; if (wave_find(h, 1024, r3, &b, &r)) sbl = b; }
            __syncthreads();
            const unsigned thr_key = (bh << 21) | (bm << 10) | (unsigned)sbl;
            for (int i = t; i < cc; i += 256)
                if (sk[i] >= thr_key) { f1 += sv1[i]; f2 += sv2[i]; fc++; }
        } else {
            // slow path: rescan boundary bin from global (general insurance)
            const int b1n = b1a[n];
            const float* Pp = outputs + (size_t)n * 2 * HWSZ;
            const float* Thp = Pp + HWSZ;
            const float* Gp = labels + (size_t)n * 2 * HWSZ;
            const float* Tp = tmask + (size_t)n * HWSZ;
            for (int i = t; i < 2048; i += 256) h[i] = 0;
            __syncthreads();
            for (int i = t; i < HWSZ; i += 256) {
                float pv = Pp[i];
                if (Gp[i] <= 0.5f && Tp[i] > 0.5f && pbin(pv) == b1n)
                    atomicAdd(&h[fkey(pv) >> 21], 1);
            }
            __syncthreads();
            if (t < 64) { int b, r; if (wave_find(h, 2048, k1, &b, &r)) { sbh = b; srh = r; } }
            __syncthreads();
            const unsigned bh = (unsigned)sbh; const int r2 = srh;
            for (int i = t; i < 2048; i += 256) h[i] = 0;
            __syncthreads();
            for (int i = t; i < HWSZ; i += 256) {
                float pv = Pp[i]; unsigned key = fkey(pv);
                if (Gp[i] <= 0.5f && Tp[i] > 0.5f && pbin(pv) == b1n && (key >> 21) == bh)
                    atomicAdd(&h[(key >> 10) & 0x7FFu], 1);
            }
            __syncthreads();
            if (t < 64) { int b, r; if (wave_find(h, 2048, r2, &b, &r)) { sbm = b; srm = r; } }
            __syncthreads();
            const unsigned bm = (unsigned)sbm; const int r3 = srm;
            for (int i = t; i < 1024; i += 256) h[i] = 0;
            __syncthreads();
            for (int i = t; i < HWSZ; i += 256) {
                float pv = Pp[i]; unsigned key = fkey(pv);
                if (Gp[i] <= 0.5f && Tp[i] > 0.5f && pbin(pv) == b1n && (key >> 10) == ((bh << 11) | bm))
                    atomicAdd(&h[key & 0x3FFu], 1);
            }
            __syncthreads();
            if (t < 64) { int b, r; if (wave_find(h, 1024, r3, &b, &r)) sbl = b; }
            __syncthreads();
            const unsigned thr_key = (bh << 21) | (bm << 10) | (unsigned)sbl;
            for (int i = t; i < HWSZ; i += 256) {
                float pv = Pp[i];
                if (Gp[i] <= 0.5f && Tp[i] > 0.5f && pbin(pv) == b1n && fkey(pv) >= thr_key) {
                    float b1v, b2v; bce_pair(pv, Thp[i], false, b1v, b2v);
                    f1 += b1v; f2 += b2v; fc++;
                }
            }
        }
        double v0 = f1, v1 = f2;
        for (int off = 32; off; off >>= 1) {
            v0 += __shfl_down(v0, off, 64);
            v1 += __shfl_down(v1, off, 64);
            fc += __shfl_down(fc, off, 64);
        }
        const int lane = t & 63, wid = t >> 6;
        if (!lane) { rd[wid][0] = v0; rd[wid][1] = v1; ri[wid] = fc; }
        __syncthreads();
        if (!t) {
            f1r = rd[0][0] + rd[1][0] + rd[2][0] + rd[3][0];
            f2r = rd[0][1] + rd[1][1] + rd[2][1] + rd[3][1];
            fcr = ri[0] + ri[1] + ri[2] + ri[3];
        }
    }
    if (!t) {
        res[n * 3 + 0] = psum[n * 2 + 0] + ab1[n] + f1r;
        res[n * 3 + 1] = psum[n * 2 + 1] + ab2[n] + f2r;
        res[n * 3 + 2] = (double)poss[n] + (double)abc[n] + (double)fcr;
    }
}

__global__ void k_fin(const double* __restrict__ res, const double* __restrict__ s3s,
                      const double* __restrict__ s4s, float* __restrict__ out) {
    if (threadIdx.x != 0 || blockIdx.x != 0) return;
    double A = 0.0, Bb = 0.0, C = 0.0, S3 = 0.0, S4 = 0.0;
    for (int n = 0; n < NS; ++n) {
        A += res[n * 3 + 0]; Bb += res[n * 3 + 1]; C += res[n * 3 + 2];
        S3 += s3s[n]; S4 += s4s[n];
    }
    double lp = (C > 0.0) ? A / C : 0.0;
    double lb = (C > 0.0) ? Bb / C : 0.0;
    double lt = S3 / (S4 + 1e-6);
    out[0] = (float)(lp + lb + 10.0 * lt);
    out[1] = (float)lp;
    out[2] = (float)lb;
    out[3] = (float)lt;
}

extern "C" void kernel_launch(void* const* d_in, const int* in_sizes, int n_in,
                              void* d_out, int out_size, void* d_ws, size_t ws_size,
                              hipStream_t stream) {
    const float* outputs = (const float*)d_in[0];
    const float* labels  = (const float*)d_in[1];
    const float* tmask   = (const float*)d_in[2];
    const float* gd      = (const float*)d_in[3];
    float* out = (float*)d_out;

    char* ws = (char*)d_ws;
    double* s3s   = (double*)ws;                 // NS
    double* s4s   = s3s + NS;                    // NS
    double* psum  = s4s + NS;                    // NS*2
    double* ab1   = psum + NS * 2;               // NS
    double* ab2   = ab1 + NS;                    // NS
    double* res   = ab2 + NS;                    // NS*3
    int* abc      = (int*)(res + NS * 3);        // NS
    int* mode     = abc + NS;                    // NS
    int* b1       = mode + NS;                   // NS
    int* k1       = b1 + NS;                     // NS
    int* poss     = k1 + NS;                     // NS
    int* cand_cnt = poss + NS;                   // NS*PADI (padded counters)
    float* part   = (float*)(cand_cnt + NS * PADI);  // NS*SBPS*SLW (fully written)
    unsigned* ck  = (unsigned*)(part + (size_t)NS * SBPS * SLW);  // NS*CAP
    float* cv1    = (float*)(ck + NS * CAP);
    float* cv2    = cv1 + NS * CAP;
    (void)cv2; (void)ws_size; (void)in_sizes; (void)n_in; (void)out_size;

    // only the padded counters need zeroing; everything else is overwritten
    hipMemsetAsync(cand_cnt, 0, NS * PADI * sizeof(int), stream);

    k_scan1<<<dim3(SBPS, NS), 256, 0, stream>>>(outputs, labels, tmask, gd, part);
    k_sel1<<<NS, 1024, 0, stream>>>(part, mode, b1, k1, poss, psum, ab1, ab2, abc, s3s, s4s);
    k_gather<<<dim3(SBPS, NS), 256, 0, stream>>>(outputs, labels, tmask, mode, b1,
                                                 cand_cnt, ck, cv1, cv2);
    k_final<<<NS, 256, 0, stream>>>(outputs, labels, tmask, mode, b1, k1, poss, cand_cnt,
                                    ck, cv1, cv2, psum, ab1, ab2, abc, res);
    k_fin<<<1, 64, 0, stream>>>(res, s3s, s4s, out);
}

// Round 10
// 51.986 us; speedup vs baseline: 1.9713x; 1.0688x over previous
//
#include <hip/hip_runtime.h>
#include <math.h>
#include <stdint.h>

#define NS    16
#define HWSZ  409600
#define NF4   102400      // float4s per sample
#define NBIN  128
#define SLW   (3*NBIN + 8) // words per block slice: hist cnt/s1/s2 + 8 scalar slots
#define CAP   4096
#define BCAP  512         // per-block LDS candidate staging
#define SBPS  100         // blocks per sample (4 pipelined iterations each)
#define PADI  32          // ints per sample for padded atomic counter (128 B)

typedef unsigned long long u64;
typedef float f32x4 __attribute__((ext_vector_type(4)));

__device__ __forceinline__ unsigned fkey(float f) {
    unsigned u = __float_as_uint(f);
    if (u == 0x80000000u) u = 0u;                 // canonicalize -0
    return (u & 0x80000000u) ? ~u : (u | 0x80000000u);
}

// bce1: BCE on p; bce2: BCE on sigmoid(50(p-t)); both with 1e-7 clipping
__device__ __forceinline__ void bce_pair(float pv, float tv, bool tc, float& o1, float& o2) {
    float pc = fminf(fmaxf(pv, 1e-7f), 1.0f - 1e-7f);
    float a = tc ? pc : 1.0f - pc;
    o1 = -__logf(a);
    float x = 50.0f * (pv - tv);
    float y = tc ? -x : x;
    float t2 = __expf(-fabsf(y));
    float sp = __logf(1.0f + t2);
    sp = (y > 0.0f) ? y + sp : sp;
    o2 = fminf(sp, 16.118095651f);
}

__device__ __forceinline__ int pbin(float p) {
    int b = (int)(p * (float)NBIN);
    return min(max(b, 0), NBIN - 1);
}

// Wave-parallel descending k-th-largest bin search over a histogram.
__device__ __forceinline__ bool wave_find(const int* __restrict__ h, int nbins, int k,
                                          int* bin_out, int* rank_out) {
    const int lane = threadIdx.x & 63;
    const int CH = nbins >> 6;
    const int topStart = nbins - 1 - lane * CH;
    int s = 0;
    for (int b = 0; b < CH; ++b) s += h[topStart - b];
    int incl = s;
    for (int off = 1; off < 64; off <<= 1) {
        int v = __shfl_up(incl, off, 64);
        if (lane >= off) incl += v;
    }
    int before = incl - s;
    if (before < k && k <= incl) {
        int c = before;
        for (int b = 0; b < CH; ++b) {
            int hb = h[topStart - b];
            c += hb;
            if (c >= k) { *bin_out = topStart - b; *rank_out = k - (c - hb); return true; }
        }
    }
    return false;
}

#define GLOAD(dst, addr) \
    asm volatile("global_load_dwordx4 %0, %1, off" : "=v"(dst) : "v"(addr))
// issue one float4 from each of the 6 streams (6 loads, mutually ordered)
#define LOADSET(Sp, St, Sg, Sq, Sm, Sd, idx) do { \
    GLOAD(Sp, P + (idx));  GLOAD(St, Th + (idx)); GLOAD(Sg, G + (idx)); \
    GLOAD(Sq, Gt + (idx)); GLOAD(Sm, T + (idx)); GLOAD(Sd, D + (idx)); } while (0)
// counted wait: N loads may remain outstanding; ties the set's registers
#define WAITSET(Sp, St, Sg, Sq, Sm, Sd, N) \
    asm volatile("s_waitcnt vmcnt(" #N ")" \
                 : "+v"(Sp), "+v"(St), "+v"(Sg), "+v"(Sq), "+v"(Sm), "+v"(Sd))

// ---------------- fat pass: double-buffered pipelined streaming -------------
__global__ void k_scan1(const float* __restrict__ outputs, const float* __restrict__ labels,
                        const float* __restrict__ tmask, const float* __restrict__ gd,
                        float* __restrict__ part) {
    __shared__ int lc[NBIN];
    __shared__ float l1[NBIN], l2[NBIN];
    __shared__ float rf[4][4];
    __shared__ int ri[4][2];
    const int t = threadIdx.x, n = blockIdx.y, lane = t & 63, wid = t >> 6;
    if (t < NBIN) { lc[t] = 0; l1[t] = 0.f; l2[t] = 0.f; }
    __syncthreads();
    const f32x4* P  = (const f32x4*)(outputs + (size_t)n * 2 * HWSZ);
    const f32x4* Th = P + NF4;
    const f32x4* G  = (const f32x4*)(labels + (size_t)n * 2 * HWSZ);
    const f32x4* Gt = G + NF4;
    const f32x4* T  = (const f32x4*)(tmask + (size_t)n * HWSZ);
    const f32x4* D  = (const f32x4*)(gd + (size_t)n * HWSZ);
    const int i0 = blockIdx.x * 1024 + t;         // 4 iterations, stride 256
    float s3 = 0.f, s4 = 0.f, p1 = 0.f, p2 = 0.f;
    int cp = 0, cn = 0;
    auto proc = [&](const f32x4& p, const f32x4& th, const f32x4& g, const f32x4& q,
                    const f32x4& m, const f32x4& d) {
#pragma unroll
        for (int e = 0; e < 4; ++e) {
            float pv = p[e], tv = th[e], gv = g[e], qv = q[e], mv = m[e], dv = d[e];
            s3 += fabsf(tv - qv) * dv;
            s4 += dv;
            bool msk = mv > 0.5f, tc = gv > 0.5f;
            if (msk) {
                float o1, o2; bce_pair(pv, tv, tc, o1, o2);
                if (tc) { p1 += o1; p2 += o2; cp++; }
                else {
                    cn++;
                    int b = pbin(pv);
                    atomicAdd(&lc[b], 1);
                    atomicAdd(&l1[b], o1);
                    atomicAdd(&l2[b], o2);
                }
            }
        }
    };
    f32x4 ap, at, ag, aq, am, ad, bp, bt, bg, bq, bm, bd;
    // steady-state pipeline: 6-12 loads always in flight until the tail
    LOADSET(ap, at, ag, aq, am, ad, i0);             // A = iter 0
    LOADSET(bp, bt, bg, bq, bm, bd, i0 + 256);       // B = iter 1
    WAITSET(ap, at, ag, aq, am, ad, 6);
    proc(ap, at, ag, aq, am, ad);
    LOADSET(ap, at, ag, aq, am, ad, i0 + 512);       // A = iter 2
    WAITSET(bp, bt, bg, bq, bm, bd, 6);
    proc(bp, bt, bg, bq, bm, bd);
    LOADSET(bp, bt, bg, bq, bm, bd, i0 + 768);       // B = iter 3
    WAITSET(ap, at, ag, aq, am, ad, 6);
    proc(ap, at, ag, aq, am, ad);
    WAITSET(bp, bt, bg, bq, bm, bd, 0);
    proc(bp, bt, bg, bq, bm, bd);
    for (int off = 32; off; off >>= 1) {
        p1 += __shfl_down(p1, off, 64);
        p2 += __shfl_down(p2, off, 64);
        s3 += __shfl_down(s3, off, 64);
        s4 += __shfl_down(s4, off, 64);
        cp += __shfl_down(cp, off, 64);
        cn += __shfl_down(cn, off, 64);
    }
    if (!lane) {
        rf[wid][0] = p1; rf[wid][1] = p2; rf[wid][2] = s3; rf[wid][3] = s4;
        ri[wid][0] = cp; ri[wid][1] = cn;
    }
    __syncthreads();
    float* slice = part + (size_t)(n * SBPS + blockIdx.x) * SLW;
    int* slice_i = (int*)slice;
    if (t < NBIN) {
        slice_i[t]            = lc[t];
        slice[NBIN + t]       = l1[t];
        slice[2 * NBIN + t]   = l2[t];
    }
    if (!t) {
        slice_i[3 * NBIN + 0] = ri[0][0] + ri[1][0] + ri[2][0] + ri[3][0];  // cp
        slice_i[3 * NBIN + 1] = ri[0][1] + ri[1][1] + ri[2][1] + ri[3][1];  // cn
        slice[3 * NBIN + 2]   = rf[0][0] + rf[1][0] + rf[2][0] + rf[3][0];  // p1
        slice[3 * NBIN + 3]   = rf[0][1] + rf[1][1] + rf[2][1] + rf[3][1];  // p2
        slice[3 * NBIN + 4]   = rf[0][2] + rf[1][2] + rf[2][2] + rf[3][2];  // s3
        slice[3 * NBIN + 5]   = rf[0][3] + rf[1][3] + rf[2][3] + rf[3][3];  // s4
    }
}

// ---------------- per-sample: reduce partials + select + suffix sums --------
// modes: 0 = threshold in boundary bin; 1 = pos only; 2 = all masked; 3 = all neg+pos
// 512 threads: 4 slice-groups of 25 for the histogram reduction.
__global__ void k_sel1(const float* __restrict__ part,
                       int* __restrict__ mode, int* __restrict__ b1o, int* __restrict__ k1o,
                       int* __restrict__ poss,
                       double* __restrict__ psum, double* __restrict__ ab1,
                       double* __restrict__ ab2, int* __restrict__ abc,
                       double* __restrict__ s3s, double* __restrict__ s4s) {
    __shared__ int lc[NBIN];
    __shared__ float l1[NBIN], l2[NBIN];
    __shared__ double sdr[8][4];
    __shared__ int sir[8][2];
    __shared__ double rda[8], rdb[8];
    __shared__ int ric[8];
    __shared__ int sb1, sk1, s_md, s_k;
    const int n = blockIdx.x, t = threadIdx.x, lane = t & 63, wid = t >> 6;
    const float* base = part + (size_t)n * SBPS * SLW;
    // ---- scalar reduction over SBPS block slices
    double p1 = 0.0, p2 = 0.0, s3 = 0.0, s4 = 0.0;
    int cp = 0, cn = 0;
    if (t < SBPS) {
        const float* sl = base + (size_t)t * SLW;
        const int* sli = (const int*)sl;
        cp = sli[3 * NBIN + 0]; cn = sli[3 * NBIN + 1];
        p1 = (double)sl[3 * NBIN + 2]; p2 = (double)sl[3 * NBIN + 3];
        s3 = (double)sl[3 * NBIN + 4]; s4 = (double)sl[3 * NBIN + 5];
    }
    for (int off = 32; off; off >>= 1) {
        p1 += __shfl_down(p1, off, 64);
        p2 += __shfl_down(p2, off, 64);
        s3 += __shfl_down(s3, off, 64);
        s4 += __shfl_down(s4, off, 64);
        cp += __shfl_down(cp, off, 64);
        cn += __shfl_down(cn, off, 64);
    }
    if (!lane) {
        sdr[wid][0] = p1; sdr[wid][1] = p2; sdr[wid][2] = s3; sdr[wid][3] = s4;
        sir[wid][0] = cp; sir[wid][1] = cn;
    }
    if (t < NBIN) { lc[t] = 0; l1[t] = 0.f; l2[t] = 0.f; }
    __syncthreads();
    if (!t) {
        int pos = 0, neg = 0;
        double a = 0.0, b = 0.0, c = 0.0, d = 0.0;
        for (int w = 0; w < 8; ++w) {
            pos += sir[w][0]; neg += sir[w][1];
            a += sdr[w][0]; b += sdr[w][1]; c += sdr[w][2]; d += sdr[w][3];
        }
        int k = pos * 3; if (k > neg) k = neg;
        int md = (pos == 0) ? 2 : ((k == 0) ? 1 : ((k == neg) ? 3 : 0));
        mode[n] = md;
        poss[n] = pos;
        psum[n * 2 + 0] = a;
        psum[n * 2 + 1] = b;
        s3s[n] = c;
        s4s[n] = d;
        s_md = md; s_k = k;
    }
    __syncthreads();
    const int md = s_md, k = s_k;
    if (md == 1) { if (!t) { ab1[n] = 0.0; ab2[n] = 0.0; abc[n] = 0; } return; }
    // ---- histogram reduction: 4 thread-groups cover 25 slices each
    {
        const int bin = t & (NBIN - 1);
        const int grp = t >> 7;               // 0..3
        const int j0 = grp * (SBPS / 4);
        const int j1 = j0 + (SBPS / 4);
        int c = 0; float a = 0.f, b = 0.f;
        for (int j = j0; j < j1; ++j) {
            const float* sl = base + (size_t)j * SLW;
            c += ((const int*)sl)[bin];
            a += sl[NBIN + bin];
            b += sl[2 * NBIN + bin];
        }
        atomicAdd(&lc[bin], c);
        atomicAdd(&l1[bin], a);
        atomicAdd(&l2[bin], b);
    }
    __syncthreads();
    int B = -1;   // md==2 or md==3: sum ALL bins
    if (md == 0) {
        if (t < 64) { int bin, r; if (wave_find(lc, NBIN, k, &bin, &r)) { sb1 = bin; sk1 = r; } }
        __syncthreads();
        B = sb1;
        if (!t) { b1o[n] = sb1; k1o[n] = sk1; }
    }
    double a1 = 0.0, a2 = 0.0; int ac = 0;
    if (t < NBIN && t > B) { a1 = (double)l1[t]; a2 = (double)l2[t]; ac = lc[t]; }
    for (int off = 32; off; off >>= 1) {
        a1 += __shfl_down(a1, off, 64);
        a2 += __shfl_down(a2, off, 64);
        ac += __shfl_down(ac, off, 64);
    }
    if (!lane) { rda[wid] = a1; rdb[wid] = a2; ric[wid] = ac; }
    __syncthreads();
    if (!t) {
        double ra = 0.0, rb = 0.0; int rc = 0;
        for (int w = 0; w < 8; ++w) { ra += rda[w]; rb += rdb[w]; rc += ric[w]; }
        ab1[n] = ra; ab2[n] = rb; abc[n] = rc;
    }
}

// ---------------- boundary-bin gather: LDS-staged, 1 atomic per block -------
__global__ void k_gather(const float* __restrict__ outputs, const float* __restrict__ labels,
                         const float* __restrict__ tmask,
                         const int* __restrict__ mode, const int* __restrict__ b1a,
                         int* __restrict__ cand_cnt, unsigned* __restrict__ ck,
                         float* __restrict__ cv1, float* __restrict__ cv2) {
    const int n = blockIdx.y;
    if (mode[n] != 0) return;   // modes 1/2/3 need no boundary refinement
    const int b1n = b1a[n];
    __shared__ int lcnt, lbase;
    __shared__ unsigned lsk[BCAP];
    __shared__ float lv1[BCAP], lv2[BCAP];
    const int t = threadIdx.x;
    if (!t) lcnt = 0;
    __syncthreads();
    const float* bp = outputs + (size_t)n * 2 * HWSZ;
    const float4* P = (const float4*)bp;
    const float* Thp = bp + HWSZ;
    const float4* G = (const float4*)(labels + (size_t)n * 2 * HWSZ);
    const float4* T = (const float4*)(tmask + (size_t)n * HWSZ);
    const int stride = SBPS * 256;
    for (int i4 = blockIdx.x * 256 + t; i4 < NF4; i4 += stride) {
        float4 p = P[i4], g = G[i4], m = T[i4];
        const float* pp = (const float*)&p;
        const float* gg = (const float*)&g;
        const float* mm = (const float*)&m;
#pragma unroll
        for (int e = 0; e < 4; ++e) {
            bool cand = (gg[e] <= 0.5f) && (mm[e] > 0.5f) && (pbin(pp[e]) == b1n);
            if (cand) {
                float o1, o2; bce_pair(pp[e], Thp[4 * i4 + e], false, o1, o2);
                int idx = atomicAdd(&lcnt, 1);
                if (idx < BCAP) { lsk[idx] = fkey(pp[e]); lv1[idx] = o1; lv2[idx] = o2; }
                else {
                    int gi = atomicAdd(&cand_cnt[n * PADI], 1);   // rare overflow path
                    if (gi < CAP) { ck[n * CAP + gi] = fkey(pp[e]); cv1[n * CAP + gi] = o1; cv2[n * CAP + gi] = o2; }
                }
            }
        }
    }
    __syncthreads();
    const int cnt = min(lcnt, BCAP);
    if (!t && cnt) lbase = atomicAdd(&cand_cnt[n * PADI], cnt);
    __syncthreads();
    if (cnt) {
        const int bb = lbase;
        for (int i = t; i < cnt; i += 256) {
            int gi = bb + i;
            if (gi < CAP) { ck[n * CAP + gi] = lsk[i]; cv1[n * CAP + gi] = lv1[i]; cv2[n * CAP + gi] = lv2[i]; }
        }
    }
}

// ---------------- per-sample finalize (plain stores) ------------------------
__global__ void k_final(const float* __restrict__ outputs, const float* __restrict__ labels,
                        const float* __restrict__ tmask,
                        const int* __restrict__ mode, const int* __restrict__ b1a,
                        const int* __restrict__ k1a, const int* __restrict__ poss,
                        const int* __restrict__ cand_cnt, const unsigned* __restrict__ ck,
                        const float* __restrict__ cv1, const float* __restrict__ cv2,
                        const double* __restrict__ psum, const double* __restrict__ ab1,
                        const double* __restrict__ ab2, const int* __restrict__ abc,
                        double* __restrict__ res) {
    __shared__ unsigned sk[CAP];
    __shared__ float sv1[CAP], sv2[CAP];
    __shared__ int h[2048];
    __shared__ int sbh, srh, sbm, srm, sbl;
    __shared__ double rd[4][2];
    __shared__ int ri[4];
    const int n = blockIdx.x, t = threadIdx.x;
    const int md = mode[n];
    double f1r = 0.0, f2r = 0.0; int fcr = 0;
    if (md == 0) {
        const int k1 = k1a[n];
        const int cc = cand_cnt[n * PADI];
        float f1 = 0.f, f2 = 0.f; int fc = 0;
        if (cc <= CAP) {
            for (int i = t; i < cc; i += 256) {
                sk[i] = ck[n * CAP + i]; sv1[i] = cv1[n * CAP + i]; sv2[i] = cv2[n * CAP + i];
            }
            for (int i = t; i < 2048; i += 256) h[i] = 0;
            __syncthreads();
            for (int i = t; i < cc; i += 256) atomicAdd(&h[sk[i] >> 21], 1);
            __syncthreads();
            if (t < 64) { int b, r; if (wave_find(h, 2048, k1, &b, &r)) { sbh = b; srh = r; } }
            __syncthreads();
            const unsigned bh = (unsigned)sbh; const int r2 = srh;
            for (int i = t; i < 2048; i += 256) h[i] = 0;
            __syncthreads();
            for (int i = t; i < cc; i += 256)
                if ((sk[i] >> 21) == bh) atomicAdd(&h[(sk[i] >> 10) & 0x7FFu], 1);
            __syncthreads();
            if (t < 64) { int b, r; if (wave_find(h, 2048, r2, &b, &r)) { sbm = b; srm = r; } }
            __syncthreads();
            const unsigned bm = (unsigned)sbm; const int r3 = srm;
            for (int i = t; i < 1024; i += 256) h[i] = 0;
            __syncthreads();
            for (int i = t; i < cc; i += 256)
                if ((sk[i] >> 10) == ((bh << 11) | bm)) atomicAdd(&h[sk[i] & 0x3FFu], 1);
            __syncthreads();
            if (t < 64) { int b, r; if (wave_find(h, 1024, r3, &b, &r)) sbl = b; }
            __syncthreads();
            const unsigned thr_key = (bh << 21) | (bm << 10) | (unsigned)sbl;
            for (int i = t; i < cc; i += 256)
                if (sk[i] >= thr_key) { f1 += sv1[i]; f2 += sv2[i]; fc++; }
        } else {
            // slow path: rescan boundary bin from global (general insurance)
            const int b1n = b1a[n];
            const float* Pp = outputs + (size_t)n * 2 * HWSZ;
            const float* Thp = Pp + HWSZ;
            const float* Gp = labels + (size_t)n * 2 * HWSZ;
            const float* Tp = tmask + (size_t)n * HWSZ;
            for (int i = t; i < 2048; i += 256) h[i] = 0;
            __syncthreads();
            for (int i = t; i < HWSZ; i += 256) {
                float pv = Pp[i];
                if (Gp[i] <= 0.5f && Tp[i] > 0.5f && pbin(pv) == b1n)
                    atomicAdd(&h[fkey(pv) >> 21], 1);
            }
            __syncthreads();
            if (t < 64) { int b, r; if (wave_find(h, 2048, k1, &b, &r)) { sbh = b; srh = r; } }
            __syncthreads();
            const unsigned bh = (unsigned)sbh; const int r2 = srh;
            for (int i = t; i < 2048; i += 256) h[i] = 0;
            __syncthreads();
            for (int i = t; i < HWSZ; i += 256) {
                float pv = Pp[i]; unsigned key = fkey(pv);
                if (Gp[i] <= 0.5f && Tp[i] > 0.5f && pbin(pv) == b1n && (key >> 21) == bh)
                    atomicAdd(&h[(key >> 10) & 0x7FFu], 1);
            }
            __syncthreads();
            if (t < 64) { int b, r; if (wave_find(h, 2048, r2, &b, &r)) { sbm = b; srm = r; } }
            __syncthreads();
            const unsigned bm = (unsigned)sbm; const int r3 = srm;
            for (int i = t; i < 1024; i += 256) h[i] = 0;
            __syncthreads();
            for (int i = t; i < HWSZ; i += 256) {
                float pv = Pp[i]; unsigned key = fkey(pv);
                if (Gp[i] <= 0.5f && Tp[i] > 0.5f && pbin(pv) == b1n && (key >> 10) == ((bh << 11) | bm))
                    atomicAdd(&h[key & 0x3FFu], 1);
            }
            __syncthreads();
            if (t < 64) { int b, r; if (wave_find(h, 1024, r3, &b, &r)) sbl = b; }
            __syncthreads();
            const unsigned thr_key = (bh << 21) | (bm << 10) | (unsigned)sbl;
            for (int i = t; i < HWSZ; i += 256) {
                float pv = Pp[i];
                if (Gp[i] <= 0.5f && Tp[i] > 0.5f && pbin(pv) == b1n && fkey(pv) >= thr_key) {
                    float b1v, b2v; bce_pair(pv, Thp[i], false, b1v, b2v);
                    f1 += b1v; f2 += b2v; fc++;
                }
            }
        }
        double v0 = f1, v1 = f2;
        for (int off = 32; off; off >>= 1) {
            v0 += __shfl_down(v0, off, 64);
            v1 += __shfl_down(v1, off, 64);
            fc += __shfl_down(fc, off, 64);
        }
        const int lane = t & 63, wid = t >> 6;
        if (!lane) { rd[wid][0] = v0; rd[wid][1] = v1; ri[wid] = fc; }
        __syncthreads();
        if (!t) {
            f1r = rd[0][0] + rd[1][0] + rd[2][0] + rd[3][0];
            f2r = rd[0][1] + rd[1][1] + rd[2][1] + rd[3][1];
            fcr = ri[0] + ri[1] + ri[2] + ri[3];
        }
    }
    if (!t) {
        res[n * 3 + 0] = psum[n * 2 + 0] + ab1[n] + f1r;
        res[n * 3 + 1] = psum[n * 2 + 1] + ab2[n] + f2r;
        res[n * 3 + 2] = (double)poss[n] + (double)abc[n] + (double)fcr;
    }
}

__global__ void k_fin(const double* __restrict__ res, const double* __restrict__ s3s,
                      const double* __restrict__ s4s, float* __restrict__ out) {
    if (threadIdx.x != 0 || blockIdx.x != 0) return;
    double A = 0.0, Bb = 0.0, C = 0.0, S3 = 0.0, S4 = 0.0;
    for (int n = 0; n < NS; ++n) {
        A += res[n * 3 + 0]; Bb += res[n * 3 + 1]; C += res[n * 3 + 2];
        S3 += s3s[n]; S4 += s4s[n];
    }
    double lp = (C > 0.0) ? A / C : 0.0;
    double lb = (C > 0.0) ? Bb / C : 0.0;
    double lt = S3 / (S4 + 1e-6);
    out[0] = (float)(lp + lb + 10.0 * lt);
    out[1] = (float)lp;
    out[2] = (float)lb;
    out[3] = (float)lt;
}

extern "C" void kernel_launch(void* const* d_in, const int* in_sizes, int n_in,
                              void* d_out, int out_size, void* d_ws, size_t ws_size,
                              hipStream_t stream) {
    const float* outputs = (const float*)d_in[0];
    const float* labels  = (const float*)d_in[1];
    const float* tmask   = (const float*)d_in[2];
    const float* gd      = (const float*)d_in[3];
    float* out = (float*)d_out;

    char* ws = (char*)d_ws;
    double* s3s   = (double*)ws;                 // NS
    double* s4s   = s3s + NS;                    // NS
    double* psum  = s4s + NS;                    // NS*2
    double* ab1   = psum + NS * 2;               // NS
    double* ab2   = ab1 + NS;                    // NS
    double* res   = ab2 + NS;                    // NS*3
    int* abc      = (int*)(res + NS * 3);        // NS
    int* mode     = abc + NS;                    // NS
    int* b1       = mode + NS;                   // NS
    int* k1       = b1 + NS;                     // NS
    int* poss     = k1 + NS;                     // NS
    int* cand_cnt = poss + NS;                   // NS*PADI (padded counters)
    float* part   = (float*)(cand_cnt + NS * PADI);  // NS*SBPS*SLW (fully written)
    unsigned* ck  = (unsigned*)(part + (size_t)NS * SBPS * SLW);  // NS*CAP
    float* cv1    = (float*)(ck + NS * CAP);
    float* cv2    = cv1 + NS * CAP;
    (void)cv2; (void)ws_size; (void)in_sizes; (void)n_in; (void)out_size;

    // only the padded counters need zeroing; everything else is overwritten
    hipMemsetAsync(cand_cnt, 0, NS * PADI * sizeof(int), stream);

    k_scan1<<<dim3(SBPS, NS), 256, 0, stream>>>(outputs, labels, tmask, gd, part);
    k_sel1<<<NS, 512, 0, stream>>>(part, mode, b1, k1, poss, psum, ab1, ab2, abc, s3s, s4s);
    k_gather<<<dim3(SBPS, NS), 256, 0, stream>>>(outputs, labels, tmask, mode, b1,
                                                 cand_cnt, ck, cv1, cv2);
    k_final<<<NS, 256, 0, stream>>>(outputs, labels, tmask, mode, b1, k1, poss, cand_cnt,
                                    ck, cv1, cv2, psum, ab1, ab2, abc, res);
    k_fin<<<1, 64, 0, stream>>>(res, s3s, s4s, out);
}